// Round 2
// baseline (1795.012 us; speedup 1.0000x reference)
//
#include <hip/hip_runtime.h>
#include <hip/hip_bf16.h>

// Shapes: B=2, L=1024, D_MODEL=1024, D_INNER=2048, D_STATE=16, D_CONV=4, DT_RANK=64
#define BATCH 2
#define SEQLEN 1024
#define DMODEL 1024
#define DINNER 2048
#define DSTATE 16
#define DTRANK 64
#define ROWS (BATCH * SEQLEN) // 2048

using bf16 = __hip_bfloat16;

__device__ __forceinline__ float to_f(float x) { return x; }
__device__ __forceinline__ float to_f(bf16 x) { return __bfloat162float(x); }
__device__ __forceinline__ void store_c(float* p, float v) { *p = v; }
__device__ __forceinline__ void store_c(bf16* p, float v) { *p = __float2bfloat16(v); }

__device__ __forceinline__ float softplus_f(float x) {
    return fmaxf(x, 0.f) + log1pf(expf(-fabsf(x)));
}
__device__ __forceinline__ float silu_f(float x) {
    return x / (1.f + expf(-x));
}

// ---------- dtype detection: bf16 inputs (flag=1) vs f32 inputs (flag=0) ----------
// True bf16 N(0,1) data has exponents clustered near 127; an f32 buffer viewed as
// bf16 has ~75% of even words with wild exponents (they're float mantissa bits).
__global__ __launch_bounds__(256) void detect_kernel(const unsigned short* hs, int* flag) {
    __shared__ int cnt[256];
    int c = 0;
    for (int i = threadIdx.x; i < 8192; i += 256) {
        int e = (hs[i] >> 7) & 0xFF;
        if (e == 0 || e == 0xFF || e < 96 || e > 159) c++;
    }
    cnt[threadIdx.x] = c;
    __syncthreads();
    for (int s = 128; s > 0; s >>= 1) {
        if (threadIdx.x < s) cnt[threadIdx.x] += cnt[threadIdx.x + s];
        __syncthreads();
    }
    if (threadIdx.x == 0) *flag = (cnt[0] < 512) ? 1 : 0;
}

// Canonicalize an input tensor to bf16 regardless of its on-device dtype.
__global__ __launch_bounds__(256) void convert_kernel(const void* __restrict__ src,
                                                      bf16* __restrict__ dst, int n,
                                                      const int* __restrict__ flag) {
    int i = blockIdx.x * 256 + threadIdx.x;
    if (i >= n) return;
    if (*flag) dst[i] = ((const bf16*)src)[i];
    else       dst[i] = __float2bfloat16(((const float*)src)[i]);
}

constexpr int EPI_NONE = 0;
constexpr int EPI_SOFTPLUS_BIAS = 1;

// C[m][n] = sum_k A[m*lda+k] * Bm[n*ldb+k]  (both K-contiguous). 64x64 tile,
// 256 threads, 4x4 acc/thread, K-tiles of 16. Requires K % 16 == 0.
template <typename TA, typename TB, typename TC, int EPI>
__global__ __launch_bounds__(256) void gemm_bt(
    const TA* __restrict__ A, int lda,
    const TB* __restrict__ Bm, int ldb,
    TC* __restrict__ C, int ldc,
    int M, int N, int K,
    const bf16* __restrict__ bias)
{
    __shared__ float As[16][65];
    __shared__ float Bs[16][65];
    const int tid = threadIdx.x;
    const int tx = tid & 15;
    const int ty = tid >> 4;
    const int m0 = blockIdx.y * 64;
    const int n0 = blockIdx.x * 64;

    float acc[4][4] = {};

    for (int k0 = 0; k0 < K; k0 += 16) {
        #pragma unroll
        for (int i = 0; i < 4; ++i) {
            int lin = tid + i * 256;
            int m = lin >> 4, k = lin & 15;
            int gm = m0 + m;
            float v = 0.f;
            if (gm < M) v = to_f(A[(size_t)gm * lda + (k0 + k)]);
            As[k][m] = v;
        }
        #pragma unroll
        for (int i = 0; i < 4; ++i) {
            int lin = tid + i * 256;
            int n = lin >> 4, k = lin & 15;
            int gn = n0 + n;
            float v = 0.f;
            if (gn < N) v = to_f(Bm[(size_t)gn * ldb + (k0 + k)]);
            Bs[k][n] = v;
        }
        __syncthreads();
        #pragma unroll
        for (int kk = 0; kk < 16; ++kk) {
            float a[4], b[4];
            #pragma unroll
            for (int i = 0; i < 4; ++i) a[i] = As[kk][ty * 4 + i];
            #pragma unroll
            for (int j = 0; j < 4; ++j) b[j] = Bs[kk][tx * 4 + j];
            #pragma unroll
            for (int i = 0; i < 4; ++i)
                #pragma unroll
                for (int j = 0; j < 4; ++j)
                    acc[i][j] = fmaf(a[i], b[j], acc[i][j]);
        }
        __syncthreads();
    }

    #pragma unroll
    for (int i = 0; i < 4; ++i) {
        int gm = m0 + ty * 4 + i;
        if (gm >= M) continue;
        #pragma unroll
        for (int j = 0; j < 4; ++j) {
            int gn = n0 + tx * 4 + j;
            if (gn >= N) continue;
            float v = acc[i][j];
            if constexpr (EPI == EPI_SOFTPLUS_BIAS) {
                v += to_f(bias[gn]);
                v = softplus_f(v);
            }
            store_c(&C[(size_t)gm * ldc + gn], v);
        }
    }
}

// Final GEMM: out = outz @ out_proj^T, stored bf16 or f32 per flag.
__global__ __launch_bounds__(256) void gemm_out(
    const bf16* __restrict__ A, int lda,
    const bf16* __restrict__ Bm, int ldb,
    void* __restrict__ C, int ldc,
    int M, int N, int K,
    const int* __restrict__ flag)
{
    __shared__ float As[16][65];
    __shared__ float Bs[16][65];
    const int tid = threadIdx.x;
    const int tx = tid & 15;
    const int ty = tid >> 4;
    const int m0 = blockIdx.y * 64;
    const int n0 = blockIdx.x * 64;

    float acc[4][4] = {};

    for (int k0 = 0; k0 < K; k0 += 16) {
        #pragma unroll
        for (int i = 0; i < 4; ++i) {
            int lin = tid + i * 256;
            int m = lin >> 4, k = lin & 15;
            As[k][m] = to_f(A[(size_t)(m0 + m) * lda + (k0 + k)]);
        }
        #pragma unroll
        for (int i = 0; i < 4; ++i) {
            int lin = tid + i * 256;
            int n = lin >> 4, k = lin & 15;
            Bs[k][n] = to_f(Bm[(size_t)(n0 + n) * ldb + (k0 + k)]);
        }
        __syncthreads();
        #pragma unroll
        for (int kk = 0; kk < 16; ++kk) {
            float a[4], b[4];
            #pragma unroll
            for (int i = 0; i < 4; ++i) a[i] = As[kk][ty * 4 + i];
            #pragma unroll
            for (int j = 0; j < 4; ++j) b[j] = Bs[kk][tx * 4 + j];
            #pragma unroll
            for (int i = 0; i < 4; ++i)
                #pragma unroll
                for (int j = 0; j < 4; ++j)
                    acc[i][j] = fmaf(a[i], b[j], acc[i][j]);
        }
        __syncthreads();
    }

    int isbf = *flag;
    #pragma unroll
    for (int i = 0; i < 4; ++i) {
        int gm = m0 + ty * 4 + i;
        #pragma unroll
        for (int j = 0; j < 4; ++j) {
            int gn = n0 + tx * 4 + j;
            size_t idx = (size_t)gm * ldc + gn;
            if (isbf) ((bf16*)C)[idx] = __float2bfloat16(acc[i][j]);
            else      ((float*)C)[idx] = acc[i][j];
        }
    }
}

// u[b,l,d] = silu(sum_k x[b,l-3+k,d]*w[d,k] + bias[d]); x = xz[...,0:2048] (row stride 4096)
__global__ __launch_bounds__(256) void conv_silu_kernel(
    const bf16* __restrict__ xz,
    const bf16* __restrict__ w,
    const bf16* __restrict__ bias,
    bf16* __restrict__ u)
{
    int idx = blockIdx.x * 256 + threadIdx.x;
    int d = idx & (DINNER - 1);
    int l = (idx >> 11) & (SEQLEN - 1);
    int b = idx >> 21;

    float acc = to_f(bias[d]);
    #pragma unroll
    for (int k = 0; k < 4; ++k) {
        int ll = l - 3 + k;
        if (ll >= 0) {
            float xv = to_f(xz[((size_t)(b * SEQLEN + ll)) * (2 * DINNER) + d]);
            acc = fmaf(xv, to_f(w[d * 4 + k]), acc);
        }
    }
    u[idx] = __float2bfloat16(silu_f(acc));
}

// One thread per (b,d,n); 16 lanes share (b,d). h = exp(delta*A)*h + delta*B*u;
// y = sum_n h*C; fused +u*D and *silu(z) epilogue.
__global__ __launch_bounds__(256) void scan_kernel(
    const float* __restrict__ delta,   // (B,L,DINNER) f32
    const bf16*  __restrict__ ut,      // (B,L,DINNER)
    const float* __restrict__ xdbl,    // (B,L,96): [64:80)=Bv, [80:96)=Cv
    const bf16*  __restrict__ xz,      // (B,L,4096): z at [2048+d]
    const bf16*  __restrict__ A_log,   // (DINNER,16)
    const bf16*  __restrict__ Dp,      // (DINNER,)
    bf16* __restrict__ outz)           // (B,L,DINNER)
{
    int t = blockIdx.x * 256 + threadIdx.x;
    int n = t & 15;
    int d = (t >> 4) & (DINNER - 1);
    int b = t >> 15;

    float Aa = -expf(to_f(A_log[d * DSTATE + n]));
    float Dv = to_f(Dp[d]);
    float h = 0.f;

    for (int l = 0; l < SEQLEN; ++l) {
        size_t row = (size_t)(b * SEQLEN + l);
        float dv = delta[row * DINNER + d];
        float uv = to_f(ut[row * DINNER + d]);
        float Bv = xdbl[row * 96 + 64 + n];
        float Cv = xdbl[row * 96 + 80 + n];
        h = fmaf(expf(dv * Aa), h, dv * Bv * uv);
        float p = h * Cv;
        p += __shfl_xor(p, 1, 16);
        p += __shfl_xor(p, 2, 16);
        p += __shfl_xor(p, 4, 16);
        p += __shfl_xor(p, 8, 16);
        if (n == 0) {
            float y = p + uv * Dv;
            float z = to_f(xz[row * (2 * DINNER) + DINNER + d]);
            outz[row * DINNER + d] = __float2bfloat16(y * silu_f(z));
        }
    }
}

extern "C" void kernel_launch(void* const* d_in, const int* in_sizes, int n_in,
                              void* d_out, int out_size, void* d_ws, size_t ws_size,
                              hipStream_t stream) {
    // Input element counts (setup_inputs order)
    static const size_t SZ[10] = {
        (size_t)BATCH * SEQLEN * DMODEL,   // hidden_states   2,097,152
        (size_t)2 * DINNER * DMODEL,       // in_proj_w       4,194,304
        (size_t)DINNER * 4,                // conv1d_w            8,192
        (size_t)DINNER,                    // conv1d_b            2,048
        (size_t)(DTRANK + 2 * DSTATE) * DINNER, // x_proj_w     196,608
        (size_t)DINNER * DTRANK,           // dt_proj_w         131,072
        (size_t)DINNER,                    // dt_proj_b           2,048
        (size_t)DINNER * DSTATE,           // A_log              32,768
        (size_t)DINNER,                    // D_param             2,048
        (size_t)DMODEL * DINNER            // out_proj_w      2,097,152
    };
    size_t tot_in = 0;
    for (int i = 0; i < 10; ++i) tot_in += SZ[i];

    char* p = (char*)d_ws;
    int* flag = (int*)p;                     p += 64;
    bf16* inb = (bf16*)p;                    p += tot_in * 2;
    bf16* xz = (bf16*)p;                     p += (size_t)ROWS * 4096 * 2;
    bf16* ut = (bf16*)p;                     p += (size_t)ROWS * 2048 * 2;
    float* xdbl = (float*)p;                 p += (size_t)ROWS * 96 * 4;
    float* delta = (float*)p;                p += (size_t)ROWS * 2048 * 4;
    bf16* outz = (bf16*)p;                   p += (size_t)ROWS * 2048 * 2;
    size_t needed = (size_t)(p - (char*)d_ws);
    if (ws_size < needed) return;  // diagnostic: out stays 0 -> absmax ~6.28 means ws too small

    dim3 blk(256);

    // 0) detect input dtype
    detect_kernel<<<1, blk, 0, stream>>>((const unsigned short*)d_in[0], flag);

    // 0b) canonicalize all inputs to bf16 in ws
    bf16* inp[10];
    {
        size_t off = 0;
        for (int i = 0; i < 10; ++i) { inp[i] = inb + off; off += SZ[i]; }
    }
    for (int i = 0; i < 10; ++i) {
        int n = (int)SZ[i];
        convert_kernel<<<(n + 255) / 256, blk, 0, stream>>>(d_in[i], inp[i], n, flag);
    }
    const bf16* hs        = inp[0];
    const bf16* in_proj_w = inp[1];
    const bf16* conv_w    = inp[2];
    const bf16* conv_b    = inp[3];
    const bf16* x_proj_w  = inp[4];
    const bf16* dt_proj_w = inp[5];
    const bf16* dt_proj_b = inp[6];
    const bf16* A_log     = inp[7];
    const bf16* Dp        = inp[8];
    const bf16* out_proj_w= inp[9];

    // 1) xz = hs @ in_proj_w^T   M=2048 N=4096 K=1024
    gemm_bt<bf16, bf16, bf16, EPI_NONE>
        <<<dim3(4096 / 64, ROWS / 64), blk, 0, stream>>>(
            hs, DMODEL, in_proj_w, DMODEL, xz, 2 * DINNER, ROWS, 2 * DINNER, DMODEL, nullptr);

    // 2) u = silu(causal depthwise conv(x) + b)
    conv_silu_kernel<<<(BATCH * SEQLEN * DINNER) / 256, blk, 0, stream>>>(xz, conv_w, conv_b, ut);

    // 3) x_dbl = u @ x_proj_w^T  M=2048 N=96 K=2048
    gemm_bt<bf16, bf16, float, EPI_NONE>
        <<<dim3(2, ROWS / 64), blk, 0, stream>>>(
            ut, DINNER, x_proj_w, DINNER, xdbl, 96, ROWS, 96, DINNER, nullptr);

    // 4) delta = softplus(dt_low @ dt_proj_w^T + dt_b)  M=2048 N=2048 K=64 (lda=96)
    gemm_bt<float, bf16, float, EPI_SOFTPLUS_BIAS>
        <<<dim3(DINNER / 64, ROWS / 64), blk, 0, stream>>>(
            xdbl, 96, dt_proj_w, DTRANK, delta, DINNER, ROWS, DINNER, DTRANK, dt_proj_b);

    // 5) selective scan + y/z epilogue -> outz
    scan_kernel<<<(BATCH * DINNER * DSTATE) / 256, blk, 0, stream>>>(
        delta, ut, xdbl, xz, A_log, Dp, outz);

    // 6) out = outz @ out_proj_w^T  M=2048 N=1024 K=2048; dtype per flag
    gemm_out<<<dim3(DMODEL / 64, ROWS / 64), blk, 0, stream>>>(
        outz, DINNER, out_proj_w, DINNER, d_out, DMODEL, ROWS, DMODEL, DINNER, flag);
}

// Round 3
// 577.270 us; speedup vs baseline: 3.1095x; 3.1095x over previous
//
#include <hip/hip_runtime.h>
#include <hip/hip_bf16.h>

// Shapes: B=2, L=1024, D_MODEL=1024, D_INNER=2048, D_STATE=16, D_CONV=4, DT_RANK=64
#define BATCH 2
#define SEQLEN 1024
#define DMODEL 1024
#define DINNER 2048
#define DSTATE 16
#define DTRANK 64
#define ROWS (BATCH * SEQLEN) // 2048

using bf16 = __hip_bfloat16;
typedef __bf16 bf16x8 __attribute__((ext_vector_type(8)));
typedef float f32x4 __attribute__((ext_vector_type(4)));

__device__ __forceinline__ float to_f(float x) { return x; }
__device__ __forceinline__ float to_f(bf16 x) { return __bfloat162float(x); }

__device__ __forceinline__ float softplus_f(float x) {
    return fmaxf(x, 0.f) + log1pf(expf(-fabsf(x)));
}
__device__ __forceinline__ float silu_f(float x) {
    return x / (1.f + expf(-x));
}

// async 16B global -> LDS (wave-uniform base + lane*16 layout)
__device__ __forceinline__ void gload16(const void* g, void* l) {
    __builtin_amdgcn_global_load_lds(
        (const __attribute__((address_space(1))) void*)g,
        (__attribute__((address_space(3))) void*)l, 16, 0, 0);
}

// ---------- dtype detection: bf16 inputs (flag=1) vs f32 inputs (flag=0) ----------
__global__ __launch_bounds__(256) void detect_kernel(const unsigned short* hs, int* flag) {
    __shared__ int cnt[256];
    int c = 0;
    for (int i = threadIdx.x; i < 8192; i += 256) {
        int e = (hs[i] >> 7) & 0xFF;
        if (e == 0 || e == 0xFF || e < 96 || e > 159) c++;
    }
    cnt[threadIdx.x] = c;
    __syncthreads();
    for (int s = 128; s > 0; s >>= 1) {
        if (threadIdx.x < s) cnt[threadIdx.x] += cnt[threadIdx.x + s];
        __syncthreads();
    }
    if (threadIdx.x == 0) *flag = (cnt[0] < 512) ? 1 : 0;
}

__global__ __launch_bounds__(256) void convert_kernel(const void* __restrict__ src,
                                                      bf16* __restrict__ dst, int n,
                                                      const int* __restrict__ flag) {
    int i = blockIdx.x * 256 + threadIdx.x;
    if (i >= n) return;
    if (*flag) dst[i] = ((const bf16*)src)[i];
    else       dst[i] = __float2bfloat16(((const float*)src)[i]);
}

__global__ __launch_bounds__(256) void zero_f32(float* p, int n) {
    int i = blockIdx.x * 256 + threadIdx.x;
    if (i < n) p[i] = 0.f;
}

// ---------------- MFMA GEMM: C[m][n] = sum_k A[m][k]*B[n][k], bf16 in, 128x128 tile ----
// BK=32, 256 threads = 4 waves (2x2), each wave 64x64 = 4x4 mfma_16x16x32 tiles.
template <bool DUAL>
__global__ __launch_bounds__(256) void gemm_mfma(
    const bf16* __restrict__ A, int lda,
    const bf16* __restrict__ Bm, int ldb,
    void* __restrict__ C, int ldc,
    int K, const int* __restrict__ flag)
{
    __shared__ __align__(16) __bf16 sA[128 * 32];
    __shared__ __align__(16) __bf16 sB[128 * 32];
    const int tid = threadIdx.x;
    const int m0 = blockIdx.y * 128;
    const int n0 = blockIdx.x * 128;
    const int wid = tid >> 6, ln = tid & 63;
    const int wy = (wid >> 1) * 64, wx = (wid & 1) * 64;
    const int q = ln >> 4, m16 = ln & 15;

    f32x4 acc[4][4] = {};

    for (int k0 = 0; k0 < K; k0 += 32) {
        #pragma unroll
        for (int i = 0; i < 2; ++i) {
            int idx = tid + i * 256;
            int r = idx >> 2, c = (idx & 3) * 8;
            gload16(&A[(size_t)(m0 + r) * lda + k0 + c], &sA[idx * 8]);
        }
        #pragma unroll
        for (int i = 0; i < 2; ++i) {
            int idx = tid + i * 256;
            int r = idx >> 2, c = (idx & 3) * 8;
            gload16(&Bm[(size_t)(n0 + r) * ldb + k0 + c], &sB[idx * 8]);
        }
        __syncthreads();
        bf16x8 a[4], b[4];
        #pragma unroll
        for (int i = 0; i < 4; ++i)
            a[i] = *(const bf16x8*)&sA[(wy + i * 16 + m16) * 32 + q * 8];
        #pragma unroll
        for (int j = 0; j < 4; ++j)
            b[j] = *(const bf16x8*)&sB[(wx + j * 16 + m16) * 32 + q * 8];
        #pragma unroll
        for (int i = 0; i < 4; ++i)
            #pragma unroll
            for (int j = 0; j < 4; ++j)
                acc[i][j] = __builtin_amdgcn_mfma_f32_16x16x32_bf16(a[i], b[j], acc[i][j], 0, 0, 0);
        __syncthreads();
    }

    bool isbf = true;
    if (DUAL) isbf = (*flag != 0);
    #pragma unroll
    for (int i = 0; i < 4; ++i) {
        #pragma unroll
        for (int j = 0; j < 4; ++j) {
            #pragma unroll
            for (int r = 0; r < 4; ++r) {
                int row = m0 + wy + i * 16 + q * 4 + r;
                int col = n0 + wx + j * 16 + m16;
                size_t idx = (size_t)row * ldc + col;
                float v = acc[i][j][r];
                if (!DUAL || isbf) ((bf16*)C)[idx] = __float2bfloat16(v);
                else               ((float*)C)[idx] = v;
            }
        }
    }
}

// ---------------- naive FMA GEMM (small shapes), A/B K-contiguous ----------------
constexpr int EPI_NONE = 0;
constexpr int EPI_SOFTPLUS_BIAS = 1;

template <typename TA, typename TB, int EPI>
__global__ __launch_bounds__(256) void gemm_bt(
    const TA* __restrict__ A, int lda,
    const TB* __restrict__ Bm, int ldb,
    float* __restrict__ C, int ldc,
    int M, int N, int K,
    const bf16* __restrict__ bias)
{
    __shared__ float As[16][65];
    __shared__ float Bs[16][65];
    const int tid = threadIdx.x;
    const int tx = tid & 15;
    const int ty = tid >> 4;
    const int m0 = blockIdx.y * 64;
    const int n0 = blockIdx.x * 64;

    float acc[4][4] = {};

    for (int k0 = 0; k0 < K; k0 += 16) {
        #pragma unroll
        for (int i = 0; i < 4; ++i) {
            int lin = tid + i * 256;
            int m = lin >> 4, k = lin & 15;
            int gm = m0 + m;
            float v = 0.f;
            if (gm < M) v = to_f(A[(size_t)gm * lda + (k0 + k)]);
            As[k][m] = v;
        }
        #pragma unroll
        for (int i = 0; i < 4; ++i) {
            int lin = tid + i * 256;
            int n = lin >> 4, k = lin & 15;
            int gn = n0 + n;
            float v = 0.f;
            if (gn < N) v = to_f(Bm[(size_t)gn * ldb + (k0 + k)]);
            Bs[k][n] = v;
        }
        __syncthreads();
        #pragma unroll
        for (int kk = 0; kk < 16; ++kk) {
            float a[4], b[4];
            #pragma unroll
            for (int i = 0; i < 4; ++i) a[i] = As[kk][ty * 4 + i];
            #pragma unroll
            for (int j = 0; j < 4; ++j) b[j] = Bs[kk][tx * 4 + j];
            #pragma unroll
            for (int i = 0; i < 4; ++i)
                #pragma unroll
                for (int j = 0; j < 4; ++j)
                    acc[i][j] = fmaf(a[i], b[j], acc[i][j]);
        }
        __syncthreads();
    }

    #pragma unroll
    for (int i = 0; i < 4; ++i) {
        int gm = m0 + ty * 4 + i;
        if (gm >= M) continue;
        #pragma unroll
        for (int j = 0; j < 4; ++j) {
            int gn = n0 + tx * 4 + j;
            if (gn >= N) continue;
            float v = acc[i][j];
            if constexpr (EPI == EPI_SOFTPLUS_BIAS) {
                v += to_f(bias[gn]);
                v = softplus_f(v);
            }
            C[(size_t)gm * ldc + gn] = v;
        }
    }
}

// split-K variant (blockIdx.z selects K-range), atomicAdd accumulate into pre-zeroed C
__global__ __launch_bounds__(256) void gemm_bt_atomic(
    const bf16* __restrict__ A, int lda,
    const bf16* __restrict__ Bm, int ldb,
    float* __restrict__ C, int ldc,
    int M, int N, int Kspl)
{
    __shared__ float As[16][65];
    __shared__ float Bs[16][65];
    const int tid = threadIdx.x;
    const int tx = tid & 15;
    const int ty = tid >> 4;
    const int m0 = blockIdx.y * 64;
    const int n0 = blockIdx.x * 64;
    const int kbeg = blockIdx.z * Kspl;

    float acc[4][4] = {};

    for (int k0 = kbeg; k0 < kbeg + Kspl; k0 += 16) {
        #pragma unroll
        for (int i = 0; i < 4; ++i) {
            int lin = tid + i * 256;
            int m = lin >> 4, k = lin & 15;
            int gm = m0 + m;
            float v = 0.f;
            if (gm < M) v = to_f(A[(size_t)gm * lda + (k0 + k)]);
            As[k][m] = v;
        }
        #pragma unroll
        for (int i = 0; i < 4; ++i) {
            int lin = tid + i * 256;
            int n = lin >> 4, k = lin & 15;
            int gn = n0 + n;
            float v = 0.f;
            if (gn < N) v = to_f(Bm[(size_t)gn * ldb + (k0 + k)]);
            Bs[k][n] = v;
        }
        __syncthreads();
        #pragma unroll
        for (int kk = 0; kk < 16; ++kk) {
            float a[4], b[4];
            #pragma unroll
            for (int i = 0; i < 4; ++i) a[i] = As[kk][ty * 4 + i];
            #pragma unroll
            for (int j = 0; j < 4; ++j) b[j] = Bs[kk][tx * 4 + j];
            #pragma unroll
            for (int i = 0; i < 4; ++i)
                #pragma unroll
                for (int j = 0; j < 4; ++j)
                    acc[i][j] = fmaf(a[i], b[j], acc[i][j]);
        }
        __syncthreads();
    }

    #pragma unroll
    for (int i = 0; i < 4; ++i) {
        int gm = m0 + ty * 4 + i;
        if (gm >= M) continue;
        #pragma unroll
        for (int j = 0; j < 4; ++j) {
            int gn = n0 + tx * 4 + j;
            if (gn >= N) continue;
            atomicAdd(&C[(size_t)gm * ldc + gn], acc[i][j]);
        }
    }
}

// u[b,l,d] = silu(conv(x)+b); x = xz[...,0:2048] (row stride 4096)
__global__ __launch_bounds__(256) void conv_silu_kernel(
    const bf16* __restrict__ xz,
    const bf16* __restrict__ w,
    const bf16* __restrict__ bias,
    bf16* __restrict__ u)
{
    int idx = blockIdx.x * 256 + threadIdx.x;
    int d = idx & (DINNER - 1);
    int l = (idx >> 11) & (SEQLEN - 1);
    int b = idx >> 21;

    float acc = to_f(bias[d]);
    #pragma unroll
    for (int k = 0; k < 4; ++k) {
        int ll = l - 3 + k;
        if (ll >= 0) {
            float xv = to_f(xz[((size_t)(b * SEQLEN + ll)) * (2 * DINNER) + d]);
            acc = fmaf(xv, to_f(w[d * 4 + k]), acc);
        }
    }
    u[idx] = __float2bfloat16(silu_f(acc));
}

// ---------------- scan v2: chunked LDS staging ----------------
// Block = 256 threads = 16 d-channels x 16 states. Grid = B * DINNER/16 = 256 blocks.
// Chunks of 64 timesteps staged cooperatively into LDS, recurrence runs from LDS.
__global__ __launch_bounds__(256) void scan_kernel2(
    const float* __restrict__ delta,   // (B,L,DINNER) f32
    const bf16*  __restrict__ ut,      // (B,L,DINNER)
    const float* __restrict__ xdbl,    // (B,L,96): [64:80)=Bv, [80:96)=Cv
    const bf16*  __restrict__ xz,      // (B,L,4096): z at [2048+d]
    const bf16*  __restrict__ A_log,   // (DINNER,16)
    const bf16*  __restrict__ Dp,      // (DINNER,)
    bf16* __restrict__ outz)           // (B,L,DINNER)
{
    __shared__ float sdel[64][17], su[64][17], ssz[64][17];
    __shared__ float sBv[64][17], sCv[64][17], sY[64][17];
    const int tid = threadIdx.x;
    const int b = blockIdx.x >> 7;
    const int d0 = (blockIdx.x & 127) * 16;
    const int g = tid >> 4, n = tid & 15;
    const int d = d0 + g;
    const size_t bL = (size_t)b * SEQLEN;

    const float Aa = -expf(to_f(A_log[d * DSTATE + n]));
    const float Dv = to_f(Dp[d]);
    float h = 0.f;

    const int j = tid & 15, r0 = tid >> 4;

    for (int c = 0; c < SEQLEN / 64; ++c) {
        const int L0 = c * 64;
        #pragma unroll
        for (int i = 0; i < 4; ++i) {
            int r = r0 + i * 16;
            size_t row = bL + L0 + r;
            sdel[r][j] = delta[row * DINNER + d0 + j];
            su[r][j]   = to_f(ut[row * DINNER + d0 + j]);
            ssz[r][j]  = silu_f(to_f(xz[row * (2 * DINNER) + DINNER + d0 + j]));
            sBv[r][j]  = xdbl[row * 96 + 64 + j];
            sCv[r][j]  = xdbl[row * 96 + 80 + j];
        }
        __syncthreads();
        #pragma unroll 4
        for (int l = 0; l < 64; ++l) {
            float dv = sdel[l][g];
            float uv = su[l][g];
            float Bv = sBv[l][n];
            float Cv = sCv[l][n];
            h = fmaf(expf(dv * Aa), h, dv * Bv * uv);
            float p = h * Cv;
            p += __shfl_xor(p, 1, 16);
            p += __shfl_xor(p, 2, 16);
            p += __shfl_xor(p, 4, 16);
            p += __shfl_xor(p, 8, 16);
            if (n == 0) sY[l][g] = (p + uv * Dv) * ssz[l][g];
        }
        __syncthreads();
        #pragma unroll
        for (int i = 0; i < 4; ++i) {
            int r = r0 + i * 16;
            outz[(bL + L0 + r) * DINNER + d0 + j] = __float2bfloat16(sY[r][j]);
        }
    }
}

extern "C" void kernel_launch(void* const* d_in, const int* in_sizes, int n_in,
                              void* d_out, int out_size, void* d_ws, size_t ws_size,
                              hipStream_t stream) {
    static const size_t SZ[10] = {
        (size_t)BATCH * SEQLEN * DMODEL,        // hidden_states
        (size_t)2 * DINNER * DMODEL,            // in_proj_w
        (size_t)DINNER * 4,                     // conv1d_w
        (size_t)DINNER,                         // conv1d_b
        (size_t)(DTRANK + 2 * DSTATE) * DINNER, // x_proj_w
        (size_t)DINNER * DTRANK,                // dt_proj_w
        (size_t)DINNER,                         // dt_proj_b
        (size_t)DINNER * DSTATE,                // A_log
        (size_t)DINNER,                         // D_param
        (size_t)DMODEL * DINNER                 // out_proj_w
    };
    size_t tot_in = 0;
    for (int i = 0; i < 10; ++i) tot_in += SZ[i];

    char* p = (char*)d_ws;
    int* flag = (int*)p;                     p += 64;
    bf16* inb = (bf16*)p;                    p += tot_in * 2;
    bf16* xz = (bf16*)p;                     p += (size_t)ROWS * 4096 * 2;
    bf16* ut = (bf16*)p;                     p += (size_t)ROWS * 2048 * 2;
    float* xdbl = (float*)p;                 p += (size_t)ROWS * 96 * 4;
    float* delta = (float*)p;                p += (size_t)ROWS * 2048 * 4;
    bf16* outz = (bf16*)p;                   p += (size_t)ROWS * 2048 * 2;
    size_t needed = (size_t)(p - (char*)d_ws);
    if (ws_size < needed) return;

    dim3 blk(256);

    detect_kernel<<<1, blk, 0, stream>>>((const unsigned short*)d_in[0], flag);

    bf16* inp[10];
    {
        size_t off = 0;
        for (int i = 0; i < 10; ++i) { inp[i] = inb + off; off += SZ[i]; }
    }
    for (int i = 0; i < 10; ++i) {
        int n = (int)SZ[i];
        convert_kernel<<<(n + 255) / 256, blk, 0, stream>>>(d_in[i], inp[i], n, flag);
    }
    const bf16* hs        = inp[0];
    const bf16* in_proj_w = inp[1];
    const bf16* conv_w    = inp[2];
    const bf16* conv_b    = inp[3];
    const bf16* x_proj_w  = inp[4];
    const bf16* dt_proj_w = inp[5];
    const bf16* dt_proj_b = inp[6];
    const bf16* A_log     = inp[7];
    const bf16* Dp        = inp[8];
    const bf16* out_proj_w= inp[9];

    // 1) xz = hs @ in_proj_w^T   M=2048 N=4096 K=1024  (MFMA)
    gemm_mfma<false><<<dim3(4096 / 128, ROWS / 128), blk, 0, stream>>>(
        hs, DMODEL, in_proj_w, DMODEL, xz, 2 * DINNER, DMODEL, nullptr);

    // 2) u = silu(causal depthwise conv(x) + b)
    conv_silu_kernel<<<(BATCH * SEQLEN * DINNER) / 256, blk, 0, stream>>>(xz, conv_w, conv_b, ut);

    // 3) x_dbl = u @ x_proj_w^T  M=2048 N=96 K=2048  (split-K=4, atomic)
    zero_f32<<<(ROWS * 96 + 255) / 256, blk, 0, stream>>>(xdbl, ROWS * 96);
    gemm_bt_atomic<<<dim3(2, ROWS / 64, 4), blk, 0, stream>>>(
        ut, DINNER, x_proj_w, DINNER, xdbl, 96, ROWS, 96, DINNER / 4);

    // 4) delta = softplus(dt_low @ dt_proj_w^T + dt_b)  M=2048 N=2048 K=64
    gemm_bt<float, bf16, EPI_SOFTPLUS_BIAS><<<dim3(DINNER / 64, ROWS / 64), blk, 0, stream>>>(
        xdbl, 96, dt_proj_w, DTRANK, delta, DINNER, ROWS, DINNER, DTRANK, dt_proj_b);

    // 5) selective scan + epilogue -> outz
    scan_kernel2<<<BATCH * (DINNER / 16), blk, 0, stream>>>(
        delta, ut, xdbl, xz, A_log, Dp, outz);

    // 6) out = outz @ out_proj_w^T  M=2048 N=1024 K=2048  (MFMA, dtype per flag)
    gemm_mfma<true><<<dim3(DMODEL / 128, ROWS / 128), blk, 0, stream>>>(
        outz, DINNER, out_proj_w, DINNER, d_out, DMODEL, DINNER, flag);
}

// Round 5
// 524.501 us; speedup vs baseline: 3.4223x; 1.1006x over previous
//
#include <hip/hip_runtime.h>
#include <hip/hip_bf16.h>

// Shapes: B=2, L=1024, D_MODEL=1024, D_INNER=2048, D_STATE=16, D_CONV=4, DT_RANK=64
#define BATCH 2
#define SEQLEN 1024
#define DMODEL 1024
#define DINNER 2048
#define DSTATE 16
#define DTRANK 64
#define ROWS (BATCH * SEQLEN) // 2048

using bf16 = __hip_bfloat16;
typedef __bf16 bf16x8 __attribute__((ext_vector_type(8)));
typedef float f32x4 __attribute__((ext_vector_type(4)));

__device__ __forceinline__ float to_f(float x) { return x; }
__device__ __forceinline__ float to_f(bf16 x) { return __bfloat162float(x); }

__device__ __forceinline__ unsigned short bf_bits(float x) {
    bf16 h = __float2bfloat16(x);
    union { bf16 b; unsigned short u; } cv;
    cv.b = h;
    return cv.u;
}

__device__ __forceinline__ float softplus_f(float x) {
    return fmaxf(x, 0.f) + log1pf(expf(-fabsf(x)));
}
__device__ __forceinline__ float silu_f(float x) {
    return x / (1.f + __expf(-x));
}

// async 16B global -> LDS (wave-uniform base + lane*16 layout)
__device__ __forceinline__ void gload16(const void* g, void* l) {
    __builtin_amdgcn_global_load_lds(
        (const __attribute__((address_space(1))) void*)g,
        (__attribute__((address_space(3))) void*)l, 16, 0, 0);
}

// ---------- dtype detection: bf16 inputs (flag=1) vs f32 inputs (flag=0) ----------
__global__ __launch_bounds__(256) void detect_kernel(const unsigned short* hs, int* flag) {
    __shared__ int cnt[256];
    int c = 0;
    for (int i = threadIdx.x; i < 8192; i += 256) {
        int e = (hs[i] >> 7) & 0xFF;
        if (e == 0 || e == 0xFF || e < 96 || e > 159) c++;
    }
    cnt[threadIdx.x] = c;
    __syncthreads();
    for (int s = 128; s > 0; s >>= 1) {
        if (threadIdx.x < s) cnt[threadIdx.x] += cnt[threadIdx.x + s];
        __syncthreads();
    }
    if (threadIdx.x == 0) *flag = (cnt[0] < 512) ? 1 : 0;
}

// ---------- fused convert of all 10 inputs to one contiguous bf16 arena ----------
struct SrcPtrs { const void* p[10]; };

// cumulative element offsets (all sizes % 4 == 0)
__device__ __constant__ const size_t SEG_OFF[11] = {
    0, 2097152, 6291456, 6299648, 6301696, 6498304,
    6629376, 6631424, 6664192, 6666240, 8763392
};

__global__ __launch_bounds__(256) void convert_all(SrcPtrs s, bf16* __restrict__ dst,
                                                   const int* __restrict__ flag) {
    size_t e = ((size_t)blockIdx.x * 256 + threadIdx.x) * 4;
    if (e >= SEG_OFF[10]) return;
    int seg = 0;
    #pragma unroll
    for (int i = 1; i < 10; ++i) if (e >= SEG_OFF[i]) seg = i;
    size_t loc = e - SEG_OFF[seg];
    if (*flag) {
        ushort4 v = ((const ushort4*)s.p[seg])[loc / 4];
        ((ushort4*)(dst + e))[0] = v;
    } else {
        float4 v = ((const float4*)s.p[seg])[loc / 4];
        ushort4 o;
        o.x = bf_bits(v.x); o.y = bf_bits(v.y);
        o.z = bf_bits(v.z); o.w = bf_bits(v.w);
        ((ushort4*)(dst + e))[0] = o;
    }
}

__global__ __launch_bounds__(256) void zero_f32(float* p, int n) {
    int i = blockIdx.x * 256 + threadIdx.x;
    if (i < n) p[i] = 0.f;
}

// ---------------- MFMA GEMM: C[m][n] = sum_k A[m][k]*B[n][k], bf16 in, 128x128 tile ----
// BK=32, 256 threads = 4 waves (2x2), each wave 64x64 = 4x4 mfma_16x16x32 tiles.
// OUTMODE: 0 = bf16 store; 2 = f32 store at C + blockIdx.z*pstride (split-K partials)
template <int OUTMODE>
__global__ __launch_bounds__(256) void gemm_mfma(
    const bf16* __restrict__ A, int lda,
    const bf16* __restrict__ Bm, int ldb,
    void* __restrict__ C, int ldc,
    int Kspl, size_t pstride)
{
    __shared__ __align__(16) __bf16 sA[128 * 32];
    __shared__ __align__(16) __bf16 sB[128 * 32];
    const int tid = threadIdx.x;
    const int m0 = blockIdx.y * 128;
    const int n0 = blockIdx.x * 128;
    const int wid = tid >> 6, ln = tid & 63;
    const int wy = (wid >> 1) * 64, wx = (wid & 1) * 64;
    const int q = ln >> 4, m16 = ln & 15;
    const int kbeg = blockIdx.z * Kspl;

    f32x4 acc[4][4] = {};

    for (int k0 = kbeg; k0 < kbeg + Kspl; k0 += 32) {
        #pragma unroll
        for (int i = 0; i < 2; ++i) {
            int idx = tid + i * 256;
            int r = idx >> 2, c = (idx & 3) * 8;
            gload16(&A[(size_t)(m0 + r) * lda + k0 + c], &sA[idx * 8]);
        }
        #pragma unroll
        for (int i = 0; i < 2; ++i) {
            int idx = tid + i * 256;
            int r = idx >> 2, c = (idx & 3) * 8;
            gload16(&Bm[(size_t)(n0 + r) * ldb + k0 + c], &sB[idx * 8]);
        }
        __syncthreads();
        bf16x8 a[4], b[4];
        #pragma unroll
        for (int i = 0; i < 4; ++i)
            a[i] = *(const bf16x8*)&sA[(wy + i * 16 + m16) * 32 + q * 8];
        #pragma unroll
        for (int j = 0; j < 4; ++j)
            b[j] = *(const bf16x8*)&sB[(wx + j * 16 + m16) * 32 + q * 8];
        #pragma unroll
        for (int i = 0; i < 4; ++i)
            #pragma unroll
            for (int j = 0; j < 4; ++j)
                acc[i][j] = __builtin_amdgcn_mfma_f32_16x16x32_bf16(a[i], b[j], acc[i][j], 0, 0, 0);
        __syncthreads();
    }

    #pragma unroll
    for (int i = 0; i < 4; ++i) {
        #pragma unroll
        for (int j = 0; j < 4; ++j) {
            #pragma unroll
            for (int r = 0; r < 4; ++r) {
                int row = m0 + wy + i * 16 + q * 4 + r;
                int col = n0 + wx + j * 16 + m16;
                size_t idx = (size_t)row * ldc + col;
                float v = acc[i][j][r];
                if constexpr (OUTMODE == 0) {
                    ((bf16*)C)[idx] = __float2bfloat16(v);
                } else {
                    ((float*)C + blockIdx.z * pstride)[idx] = v;
                }
            }
        }
    }
}

// sum the two split-K partials, store to d_out as bf16 or f32 per flag
__global__ __launch_bounds__(256) void sum_store(
    const float* __restrict__ p0, const float* __restrict__ p1,
    void* __restrict__ out, const int* __restrict__ flag, int n4)
{
    int i = blockIdx.x * 256 + threadIdx.x;
    if (i >= n4) return;
    float4 a = ((const float4*)p0)[i];
    float4 b = ((const float4*)p1)[i];
    float4 sv; sv.x = a.x + b.x; sv.y = a.y + b.y; sv.z = a.z + b.z; sv.w = a.w + b.w;
    if (*flag) {
        ushort4 o;
        o.x = bf_bits(sv.x); o.y = bf_bits(sv.y);
        o.z = bf_bits(sv.z); o.w = bf_bits(sv.w);
        ((ushort4*)out)[i] = o;
    } else {
        ((float4*)out)[i] = sv;
    }
}

// ---------------- naive FMA GEMM (small shapes), A/B K-contiguous ----------------
constexpr int EPI_NONE = 0;
constexpr int EPI_SOFTPLUS_BIAS = 1;

template <typename TA, typename TB, int EPI>
__global__ __launch_bounds__(256) void gemm_bt(
    const TA* __restrict__ A, int lda,
    const TB* __restrict__ Bm, int ldb,
    float* __restrict__ C, int ldc,
    int M, int N, int K,
    const bf16* __restrict__ bias)
{
    __shared__ float As[16][65];
    __shared__ float Bs[16][65];
    const int tid = threadIdx.x;
    const int tx = tid & 15;
    const int ty = tid >> 4;
    const int m0 = blockIdx.y * 64;
    const int n0 = blockIdx.x * 64;

    float acc[4][4] = {};

    for (int k0 = 0; k0 < K; k0 += 16) {
        #pragma unroll
        for (int i = 0; i < 4; ++i) {
            int lin = tid + i * 256;
            int m = lin >> 4, k = lin & 15;
            int gm = m0 + m;
            float v = 0.f;
            if (gm < M) v = to_f(A[(size_t)gm * lda + (k0 + k)]);
            As[k][m] = v;
        }
        #pragma unroll
        for (int i = 0; i < 4; ++i) {
            int lin = tid + i * 256;
            int n = lin >> 4, k = lin & 15;
            int gn = n0 + n;
            float v = 0.f;
            if (gn < N) v = to_f(Bm[(size_t)gn * ldb + (k0 + k)]);
            Bs[k][n] = v;
        }
        __syncthreads();
        #pragma unroll
        for (int kk = 0; kk < 16; ++kk) {
            float a[4], b[4];
            #pragma unroll
            for (int i = 0; i < 4; ++i) a[i] = As[kk][ty * 4 + i];
            #pragma unroll
            for (int j = 0; j < 4; ++j) b[j] = Bs[kk][tx * 4 + j];
            #pragma unroll
            for (int i = 0; i < 4; ++i)
                #pragma unroll
                for (int j = 0; j < 4; ++j)
                    acc[i][j] = fmaf(a[i], b[j], acc[i][j]);
        }
        __syncthreads();
    }

    #pragma unroll
    for (int i = 0; i < 4; ++i) {
        int gm = m0 + ty * 4 + i;
        if (gm >= M) continue;
        #pragma unroll
        for (int j = 0; j < 4; ++j) {
            int gn = n0 + tx * 4 + j;
            if (gn >= N) continue;
            float v = acc[i][j];
            if constexpr (EPI == EPI_SOFTPLUS_BIAS) {
                v += to_f(bias[gn]);
                v = softplus_f(v);
            }
            C[(size_t)gm * ldc + gn] = v;
        }
    }
}

// split-K variant, atomicAdd into pre-zeroed C
__global__ __launch_bounds__(256) void gemm_bt_atomic(
    const bf16* __restrict__ A, int lda,
    const bf16* __restrict__ Bm, int ldb,
    float* __restrict__ C, int ldc,
    int M, int N, int Kspl)
{
    __shared__ float As[16][65];
    __shared__ float Bs[16][65];
    const int tid = threadIdx.x;
    const int tx = tid & 15;
    const int ty = tid >> 4;
    const int m0 = blockIdx.y * 64;
    const int n0 = blockIdx.x * 64;
    const int kbeg = blockIdx.z * Kspl;

    float acc[4][4] = {};

    for (int k0 = kbeg; k0 < kbeg + Kspl; k0 += 16) {
        #pragma unroll
        for (int i = 0; i < 4; ++i) {
            int lin = tid + i * 256;
            int m = lin >> 4, k = lin & 15;
            int gm = m0 + m;
            float v = 0.f;
            if (gm < M) v = to_f(A[(size_t)gm * lda + (k0 + k)]);
            As[k][m] = v;
        }
        #pragma unroll
        for (int i = 0; i < 4; ++i) {
            int lin = tid + i * 256;
            int n = lin >> 4, k = lin & 15;
            int gn = n0 + n;
            float v = 0.f;
            if (gn < N) v = to_f(Bm[(size_t)gn * ldb + (k0 + k)]);
            Bs[k][n] = v;
        }
        __syncthreads();
        #pragma unroll
        for (int kk = 0; kk < 16; ++kk) {
            float a[4], b[4];
            #pragma unroll
            for (int i = 0; i < 4; ++i) a[i] = As[kk][ty * 4 + i];
            #pragma unroll
            for (int j = 0; j < 4; ++j) b[j] = Bs[kk][tx * 4 + j];
            #pragma unroll
            for (int i = 0; i < 4; ++i)
                #pragma unroll
                for (int j = 0; j < 4; ++j)
                    acc[i][j] = fmaf(a[i], b[j], acc[i][j]);
        }
        __syncthreads();
    }

    #pragma unroll
    for (int i = 0; i < 4; ++i) {
        int gm = m0 + ty * 4 + i;
        if (gm >= M) continue;
        #pragma unroll
        for (int j = 0; j < 4; ++j) {
            int gn = n0 + tx * 4 + j;
            if (gn >= N) continue;
            atomicAdd(&C[(size_t)gm * ldc + gn], acc[i][j]);
        }
    }
}

// u[b,l,d] = silu(conv(x)+b); x = xz[...,0:2048] (row stride 4096)
__global__ __launch_bounds__(256) void conv_silu_kernel(
    const bf16* __restrict__ xz,
    const bf16* __restrict__ w,
    const bf16* __restrict__ bias,
    bf16* __restrict__ u)
{
    int idx = blockIdx.x * 256 + threadIdx.x;
    int d = idx & (DINNER - 1);
    int l = (idx >> 11) & (SEQLEN - 1);
    int b = idx >> 21;

    float acc = to_f(bias[d]);
    #pragma unroll
    for (int k = 0; k < 4; ++k) {
        int ll = l - 3 + k;
        if (ll >= 0) {
            float xv = to_f(xz[((size_t)(b * SEQLEN + ll)) * (2 * DINNER) + d]);
            acc = fmaf(xv, to_f(w[d * 4 + k]), acc);
        }
    }
    u[idx] = __float2bfloat16(silu_f(acc));
}

// ---------------- scan v3: chunk-parallel (associative linear recurrence) ----------
// Block = 256 thr = 4 L-chunks(waves) x 4 d x 16 n; grid = BATCH * DINNER/4 = 1024.
// Phase1: each wave scans its 256-step chunk from h=0, tracking product P.
// Phase2: each wave folds preceding chunk summaries (<=3 fma, wave-uniform loop).
// Phase3: rescan with correct h_in; exact same fma sequence as serial => identical.
__global__ __launch_bounds__(256) void scan_kernel3(
    const float* __restrict__ delta,   // (B,L,DINNER) f32
    const bf16*  __restrict__ ut,      // (B,L,DINNER)
    const float* __restrict__ xdbl,    // (B,L,96): [64:80)=Bv, [80:96)=Cv
    const bf16*  __restrict__ xz,      // (B,L,4096): z at [2048+d]
    const bf16*  __restrict__ A_log,   // (DINNER,16)
    const bf16*  __restrict__ Dp,      // (DINNER,)
    bf16* __restrict__ outz)           // (B,L,DINNER)
{
    __shared__ float sH[4][64], sP[4][64];
    const int tid = threadIdx.x;
    const int c = tid >> 6;            // chunk (== wave id)
    const int w = tid & 63;
    const int dg = (tid >> 4) & 3;
    const int n = tid & 15;
    const int b = blockIdx.x >> 9;
    const int d = ((blockIdx.x & 511) << 2) + dg;
    const size_t bL = (size_t)b * SEQLEN;
    const int L0 = c * (SEQLEN / 4);

    const float Aa = -__expf(to_f(A_log[d * DSTATE + n]));
    const float Dv = to_f(Dp[d]);

    // phase 1: local scan + running product
    float h = 0.f, P = 1.f;
    #pragma unroll 4
    for (int i = 0; i < SEQLEN / 4; ++i) {
        size_t row = bL + L0 + i;
        float dv = delta[row * DINNER + d];
        float uv = to_f(ut[row * DINNER + d]);
        float Bv = xdbl[row * 96 + 64 + n];
        float a = __expf(dv * Aa);
        h = fmaf(a, h, dv * Bv * uv);
        P *= a;
    }
    sH[c][w] = h;
    sP[c][w] = P;
    __syncthreads();

    // phase 2: fold preceding chunks (loop bound wave-uniform)
    float hin = 0.f;
    for (int cc = 0; cc < c; ++cc)
        hin = fmaf(sP[cc][w], hin, sH[cc][w]);

    // phase 3: rescan with correct incoming state, fused epilogue
    h = hin;
    #pragma unroll 2
    for (int i = 0; i < SEQLEN / 4; ++i) {
        size_t row = bL + L0 + i;
        float dv = delta[row * DINNER + d];
        float uv = to_f(ut[row * DINNER + d]);
        float Bv = xdbl[row * 96 + 64 + n];
        float Cv = xdbl[row * 96 + 80 + n];
        float a = __expf(dv * Aa);
        h = fmaf(a, h, dv * Bv * uv);
        float p = h * Cv;
        p += __shfl_xor(p, 1, 16);
        p += __shfl_xor(p, 2, 16);
        p += __shfl_xor(p, 4, 16);
        p += __shfl_xor(p, 8, 16);
        if (n == 0) {
            float z = to_f(xz[row * (2 * DINNER) + DINNER + d]);
            outz[row * DINNER + d] = __float2bfloat16((p + uv * Dv) * silu_f(z));
        }
    }
}

extern "C" void kernel_launch(void* const* d_in, const int* in_sizes, int n_in,
                              void* d_out, int out_size, void* d_ws, size_t ws_size,
                              hipStream_t stream) {
    static const size_t SZ[10] = {
        (size_t)BATCH * SEQLEN * DMODEL,        // hidden_states
        (size_t)2 * DINNER * DMODEL,            // in_proj_w
        (size_t)DINNER * 4,                     // conv1d_w
        (size_t)DINNER,                         // conv1d_b
        (size_t)(DTRANK + 2 * DSTATE) * DINNER, // x_proj_w
        (size_t)DINNER * DTRANK,                // dt_proj_w
        (size_t)DINNER,                         // dt_proj_b
        (size_t)DINNER * DSTATE,                // A_log
        (size_t)DINNER,                         // D_param
        (size_t)DMODEL * DINNER                 // out_proj_w
    };
    size_t tot_in = 0;
    for (int i = 0; i < 10; ++i) tot_in += SZ[i];

    char* p = (char*)d_ws;
    int* flag = (int*)p;                     p += 64;
    bf16* inb = (bf16*)p;                    p += tot_in * 2;
    bf16* xz = (bf16*)p;                     p += (size_t)ROWS * 4096 * 2;
    bf16* ut = (bf16*)p;                     p += (size_t)ROWS * 2048 * 2;
    float* xdbl = (float*)p;                 p += (size_t)ROWS * 96 * 4;
    float* delta = (float*)p;                p += (size_t)ROWS * 2048 * 4;
    bf16* outz = (bf16*)p;                   p += (size_t)ROWS * 2048 * 2;
    float* part = (float*)p;                 p += (size_t)2 * ROWS * DMODEL * 4;
    size_t needed = (size_t)(p - (char*)d_ws);
    if (ws_size < needed) return;

    dim3 blk(256);

    detect_kernel<<<1, blk, 0, stream>>>((const unsigned short*)d_in[0], flag);

    bf16* inp[10];
    {
        size_t off = 0;
        for (int i = 0; i < 10; ++i) { inp[i] = inb + off; off += SZ[i]; }
    }
    SrcPtrs sp;
    for (int i = 0; i < 10; ++i) sp.p[i] = d_in[i];
    convert_all<<<(int)((tot_in / 4 + 255) / 256), blk, 0, stream>>>(sp, inb, flag);

    const bf16* hs        = inp[0];
    const bf16* in_proj_w = inp[1];
    const bf16* conv_w    = inp[2];
    const bf16* conv_b    = inp[3];
    const bf16* x_proj_w  = inp[4];
    const bf16* dt_proj_w = inp[5];
    const bf16* dt_proj_b = inp[6];
    const bf16* A_log     = inp[7];
    const bf16* Dp        = inp[8];
    const bf16* out_proj_w= inp[9];

    // 1) xz = hs @ in_proj_w^T   M=2048 N=4096 K=1024  (MFMA)
    gemm_mfma<0><<<dim3(4096 / 128, ROWS / 128, 1), blk, 0, stream>>>(
        hs, DMODEL, in_proj_w, DMODEL, xz, 2 * DINNER, DMODEL, 0);

    // 2) u = silu(causal depthwise conv(x) + b)
    conv_silu_kernel<<<(BATCH * SEQLEN * DINNER) / 256, blk, 0, stream>>>(xz, conv_w, conv_b, ut);

    // 3) x_dbl = u @ x_proj_w^T  M=2048 N=96 K=2048  (split-K=4, atomic)
    zero_f32<<<(ROWS * 96 + 255) / 256, blk, 0, stream>>>(xdbl, ROWS * 96);
    gemm_bt_atomic<<<dim3(2, ROWS / 64, 4), blk, 0, stream>>>(
        ut, DINNER, x_proj_w, DINNER, xdbl, 96, ROWS, 96, DINNER / 4);

    // 4) delta = softplus(dt_low @ dt_proj_w^T + dt_b)  M=2048 N=2048 K=64
    gemm_bt<float, bf16, EPI_SOFTPLUS_BIAS><<<dim3(DINNER / 64, ROWS / 64), blk, 0, stream>>>(
        xdbl, 96, dt_proj_w, DTRANK, delta, DINNER, ROWS, DINNER, DTRANK, dt_proj_b);

    // 5) chunk-parallel selective scan + epilogue -> outz
    scan_kernel3<<<BATCH * (DINNER / 4), blk, 0, stream>>>(
        delta, ut, xdbl, xz, A_log, Dp, outz);

    // 6) out = outz @ out_proj_w^T  M=2048 N=1024 K=2048  (MFMA split-K=2 -> f32 partials)
    gemm_mfma<2><<<dim3(DMODEL / 128, ROWS / 128, 2), blk, 0, stream>>>(
        outz, DINNER, out_proj_w, DINNER, part, DMODEL, DINNER / 2, (size_t)ROWS * DMODEL);

    // 6b) out = cvt(part0 + part1)
    sum_store<<<(ROWS * DMODEL / 4 + 255) / 256, blk, 0, stream>>>(
        part, part + (size_t)ROWS * DMODEL, d_out, flag, ROWS * DMODEL / 4);
}

// Round 6
// 453.537 us; speedup vs baseline: 3.9578x; 1.1565x over previous
//
#include <hip/hip_runtime.h>
#include <hip/hip_bf16.h>

// Shapes: B=2, L=1024, D_MODEL=1024, D_INNER=2048, D_STATE=16, D_CONV=4, DT_RANK=64
#define BATCH 2
#define SEQLEN 1024
#define DMODEL 1024
#define DINNER 2048
#define DSTATE 16
#define DTRANK 64
#define ROWS (BATCH * SEQLEN) // 2048

using bf16 = __hip_bfloat16;
typedef __bf16 bf16x8 __attribute__((ext_vector_type(8)));
typedef float f32x4 __attribute__((ext_vector_type(4)));

__device__ __forceinline__ float to_f(float x) { return x; }
__device__ __forceinline__ float to_f(bf16 x) { return __bfloat162float(x); }

__device__ __forceinline__ unsigned short bf_bits(float x) {
    bf16 h = __float2bfloat16(x);
    union { bf16 b; unsigned short u; } cv;
    cv.b = h;
    return cv.u;
}

__device__ __forceinline__ float softplus_f(float x) {
    return fmaxf(x, 0.f) + log1pf(expf(-fabsf(x)));
}
__device__ __forceinline__ float silu_f(float x) {
    return x / (1.f + __expf(-x));
}

// async 16B global -> LDS (wave-uniform base + lane*16 layout)
__device__ __forceinline__ void gload16(const void* g, void* l) {
    __builtin_amdgcn_global_load_lds(
        (const __attribute__((address_space(1))) void*)g,
        (__attribute__((address_space(3))) void*)l, 16, 0, 0);
}

// ---------- dtype detection: bf16 inputs (flag=1) vs f32 inputs (flag=0) ----------
__global__ __launch_bounds__(256) void detect_kernel(const unsigned short* hs, int* flag) {
    __shared__ int cnt[256];
    int c = 0;
    for (int i = threadIdx.x; i < 8192; i += 256) {
        int e = (hs[i] >> 7) & 0xFF;
        if (e == 0 || e == 0xFF || e < 96 || e > 159) c++;
    }
    cnt[threadIdx.x] = c;
    __syncthreads();
    for (int s = 128; s > 0; s >>= 1) {
        if (threadIdx.x < s) cnt[threadIdx.x] += cnt[threadIdx.x + s];
        __syncthreads();
    }
    if (threadIdx.x == 0) *flag = (cnt[0] < 512) ? 1 : 0;
}

// ---------- fused convert of all 10 inputs to one contiguous bf16 arena ----------
struct SrcPtrs { const void* p[10]; };

__device__ __constant__ const size_t SEG_OFF[11] = {
    0, 2097152, 6291456, 6299648, 6301696, 6498304,
    6629376, 6631424, 6664192, 6666240, 8763392
};

__global__ __launch_bounds__(256) void convert_all(SrcPtrs s, bf16* __restrict__ dst,
                                                   const int* __restrict__ flag) {
    size_t e = ((size_t)blockIdx.x * 256 + threadIdx.x) * 4;
    if (e >= SEG_OFF[10]) return;
    int seg = 0;
    #pragma unroll
    for (int i = 1; i < 10; ++i) if (e >= SEG_OFF[i]) seg = i;
    size_t loc = e - SEG_OFF[seg];
    if (*flag) {
        ushort4 v = ((const ushort4*)s.p[seg])[loc / 4];
        ((ushort4*)(dst + e))[0] = v;
    } else {
        float4 v = ((const float4*)s.p[seg])[loc / 4];
        ushort4 o;
        o.x = bf_bits(v.x); o.y = bf_bits(v.y);
        o.z = bf_bits(v.z); o.w = bf_bits(v.w);
        ((ushort4*)(dst + e))[0] = o;
    }
}

__global__ __launch_bounds__(256) void zero_f32(float* p, int n) {
    int i = blockIdx.x * 256 + threadIdx.x;
    if (i < n) p[i] = 0.f;
}

// ---------------- MFMA GEMM: C[m][n] = sum_k A[m][k]*B[n][k], bf16 in, 128x128 tile ----
// OUTMODE: 0 = bf16 store; 2 = f32 store at C + blockIdx.z*pstride (split-K partials)
template <int OUTMODE>
__global__ __launch_bounds__(256) void gemm_mfma(
    const bf16* __restrict__ A, int lda,
    const bf16* __restrict__ Bm, int ldb,
    void* __restrict__ C, int ldc,
    int Kspl, size_t pstride)
{
    __shared__ __align__(16) __bf16 sA[128 * 32];
    __shared__ __align__(16) __bf16 sB[128 * 32];
    const int tid = threadIdx.x;
    const int m0 = blockIdx.y * 128;
    const int n0 = blockIdx.x * 128;
    const int wid = tid >> 6, ln = tid & 63;
    const int wy = (wid >> 1) * 64, wx = (wid & 1) * 64;
    const int q = ln >> 4, m16 = ln & 15;
    const int kbeg = blockIdx.z * Kspl;

    f32x4 acc[4][4] = {};

    for (int k0 = kbeg; k0 < kbeg + Kspl; k0 += 32) {
        #pragma unroll
        for (int i = 0; i < 2; ++i) {
            int idx = tid + i * 256;
            int r = idx >> 2, c = (idx & 3) * 8;
            gload16(&A[(size_t)(m0 + r) * lda + k0 + c], &sA[idx * 8]);
        }
        #pragma unroll
        for (int i = 0; i < 2; ++i) {
            int idx = tid + i * 256;
            int r = idx >> 2, c = (idx & 3) * 8;
            gload16(&Bm[(size_t)(n0 + r) * ldb + k0 + c], &sB[idx * 8]);
        }
        __syncthreads();
        bf16x8 a[4], b[4];
        #pragma unroll
        for (int i = 0; i < 4; ++i)
            a[i] = *(const bf16x8*)&sA[(wy + i * 16 + m16) * 32 + q * 8];
        #pragma unroll
        for (int j = 0; j < 4; ++j)
            b[j] = *(const bf16x8*)&sB[(wx + j * 16 + m16) * 32 + q * 8];
        #pragma unroll
        for (int i = 0; i < 4; ++i)
            #pragma unroll
            for (int j = 0; j < 4; ++j)
                acc[i][j] = __builtin_amdgcn_mfma_f32_16x16x32_bf16(a[i], b[j], acc[i][j], 0, 0, 0);
        __syncthreads();
    }

    #pragma unroll
    for (int i = 0; i < 4; ++i) {
        #pragma unroll
        for (int j = 0; j < 4; ++j) {
            #pragma unroll
            for (int r = 0; r < 4; ++r) {
                int row = m0 + wy + i * 16 + q * 4 + r;
                int col = n0 + wx + j * 16 + m16;
                size_t idx = (size_t)row * ldc + col;
                float v = acc[i][j][r];
                if constexpr (OUTMODE == 0) {
                    ((bf16*)C)[idx] = __float2bfloat16(v);
                } else {
                    ((float*)C + blockIdx.z * pstride)[idx] = v;
                }
            }
        }
    }
}

// sum the two split-K partials, store to d_out as bf16 or f32 per flag
__global__ __launch_bounds__(256) void sum_store(
    const float* __restrict__ p0, const float* __restrict__ p1,
    void* __restrict__ out, const int* __restrict__ flag, int n4)
{
    int i = blockIdx.x * 256 + threadIdx.x;
    if (i >= n4) return;
    float4 a = ((const float4*)p0)[i];
    float4 b = ((const float4*)p1)[i];
    float4 sv; sv.x = a.x + b.x; sv.y = a.y + b.y; sv.z = a.z + b.z; sv.w = a.w + b.w;
    if (*flag) {
        ushort4 o;
        o.x = bf_bits(sv.x); o.y = bf_bits(sv.y);
        o.z = bf_bits(sv.z); o.w = bf_bits(sv.w);
        ((ushort4*)out)[i] = o;
    } else {
        ((float4*)out)[i] = sv;
    }
}

// ---------------- gemm_bt: C[m][n] = sum_k A[m][k]*B[n][k] ----------------
// EPI 2: v = softplus(v + bias[m])   (bias indexed by M — used for deltaT)
template <typename TA, typename TB, int EPI>
__global__ __launch_bounds__(256) void gemm_bt(
    const TA* __restrict__ A, int lda,
    const TB* __restrict__ Bm, int ldb,
    float* __restrict__ C, int ldc,
    int M, int N, int K,
    const bf16* __restrict__ bias)
{
    __shared__ float As[16][65];
    __shared__ float Bs[16][65];
    const int tid = threadIdx.x;
    const int tx = tid & 15;
    const int ty = tid >> 4;
    const int m0 = blockIdx.y * 64;
    const int n0 = blockIdx.x * 64;

    float acc[4][4] = {};

    for (int k0 = 0; k0 < K; k0 += 16) {
        #pragma unroll
        for (int i = 0; i < 4; ++i) {
            int lin = tid + i * 256;
            int m = lin >> 4, k = lin & 15;
            int gm = m0 + m;
            float v = 0.f;
            if (gm < M) v = to_f(A[(size_t)gm * lda + (k0 + k)]);
            As[k][m] = v;
        }
        #pragma unroll
        for (int i = 0; i < 4; ++i) {
            int lin = tid + i * 256;
            int n = lin >> 4, k = lin & 15;
            int gn = n0 + n;
            float v = 0.f;
            if (gn < N) v = to_f(Bm[(size_t)gn * ldb + (k0 + k)]);
            Bs[k][n] = v;
        }
        __syncthreads();
        #pragma unroll
        for (int kk = 0; kk < 16; ++kk) {
            float a[4], b[4];
            #pragma unroll
            for (int i = 0; i < 4; ++i) a[i] = As[kk][ty * 4 + i];
            #pragma unroll
            for (int j = 0; j < 4; ++j) b[j] = Bs[kk][tx * 4 + j];
            #pragma unroll
            for (int i = 0; i < 4; ++i)
                #pragma unroll
                for (int j = 0; j < 4; ++j)
                    acc[i][j] = fmaf(a[i], b[j], acc[i][j]);
        }
        __syncthreads();
    }

    #pragma unroll
    for (int i = 0; i < 4; ++i) {
        int gm = m0 + ty * 4 + i;
        if (gm >= M) continue;
        #pragma unroll
        for (int j = 0; j < 4; ++j) {
            int gn = n0 + tx * 4 + j;
            if (gn >= N) continue;
            float v = acc[i][j];
            if constexpr (EPI == 2) {
                v += to_f(bias[gm]);
                v = softplus_f(v);
            }
            C[(size_t)gm * ldc + gn] = v;
        }
    }
}

// ---------------- gemm_tn: C[i][j] = sum_k A[k][i] * B[j][k] ----------------
// A is K-major (d-major utT), B K-contig. split-K over blockIdx.z, atomicAdd out.
__global__ __launch_bounds__(256) void gemm_tn_atomic(
    const bf16* __restrict__ A, int lda,   // A[k][i], lda = i-stride (ROWS)
    const bf16* __restrict__ Bm, int ldb,  // B[j][k]
    float* __restrict__ C, int ldc,
    int M, int N, int Kspl)
{
    __shared__ float As[16][65];
    __shared__ float Bs[16][65];
    const int tid = threadIdx.x;
    const int tx = tid & 15;
    const int ty = tid >> 4;
    const int i0 = blockIdx.y * 64;
    const int j0 = blockIdx.x * 64;
    const int kbeg = blockIdx.z * Kspl;

    float acc[4][4] = {};

    const int li = tid & 63, lk = tid >> 6;   // A-load: 64 i x 4 k per pass

    for (int k0 = kbeg; k0 < kbeg + Kspl; k0 += 16) {
        #pragma unroll
        for (int it = 0; it < 4; ++it) {
            int k = lk + it * 4;
            As[k][li] = to_f(A[(size_t)(k0 + k) * lda + i0 + li]);
        }
        #pragma unroll
        for (int it = 0; it < 4; ++it) {
            int lin = tid + it * 256;
            int j = lin >> 4, k = lin & 15;
            int gj = j0 + j;
            float v = 0.f;
            if (gj < N) v = to_f(Bm[(size_t)gj * ldb + (k0 + k)]);
            Bs[k][j] = v;
        }
        __syncthreads();
        #pragma unroll
        for (int kk = 0; kk < 16; ++kk) {
            float a[4], b[4];
            #pragma unroll
            for (int i = 0; i < 4; ++i) a[i] = As[kk][ty * 4 + i];
            #pragma unroll
            for (int j = 0; j < 4; ++j) b[j] = Bs[kk][tx * 4 + j];
            #pragma unroll
            for (int i = 0; i < 4; ++i)
                #pragma unroll
                for (int j = 0; j < 4; ++j)
                    acc[i][j] = fmaf(a[i], b[j], acc[i][j]);
        }
        __syncthreads();
    }

    #pragma unroll
    for (int i = 0; i < 4; ++i) {
        int gi = i0 + ty * 4 + i;
        #pragma unroll
        for (int j = 0; j < 4; ++j) {
            int gj = j0 + tx * 4 + j;
            if (gj >= N) continue;
            atomicAdd(&C[(size_t)gi * ldc + gj], acc[i][j]);
        }
    }
}

// u^T[d][row] = silu(conv(x^T)+b); x^T = xzT rows 0..2048, row = b*1024+l
__global__ __launch_bounds__(256) void conv_silu_T(
    const bf16* __restrict__ xzT,
    const bf16* __restrict__ w,
    const bf16* __restrict__ bias,
    bf16* __restrict__ utT)
{
    int t = blockIdx.x * 256 + threadIdx.x;   // d*ROWS + row
    int row = t & (ROWS - 1);
    int d = t >> 11;
    int l = row & (SEQLEN - 1);

    const bf16* xp = xzT + (size_t)d * ROWS + row;
    float acc = to_f(bias[d]);
    #pragma unroll
    for (int k = 0; k < 4; ++k) {
        int ll = l - 3 + k;
        if (ll >= 0) acc = fmaf(to_f(xp[k - 3]), to_f(w[d * 4 + k]), acc);
    }
    utT[t] = __float2bfloat16(silu_f(acc));
}

// ---------------- scan v4: chunk-parallel, d-major coalesced streams ----------
// Block = 256 thr = 4 L-chunks(waves) x 4 d x 16 n; grid = BATCH * DINNER/4 = 1024.
__global__ __launch_bounds__(256) void scan_kernel4(
    const float* __restrict__ deltaT,  // (DINNER, ROWS) f32
    const bf16*  __restrict__ utT,     // (DINNER, ROWS)
    const float* __restrict__ xdbl,    // (ROWS, 96): [64:80)=Bv, [80:96)=Cv
    const bf16*  __restrict__ xzT,     // (4096, ROWS): z at row DINNER+d
    const bf16*  __restrict__ A_log,   // (DINNER,16)
    const bf16*  __restrict__ Dp,      // (DINNER,)
    bf16* __restrict__ outz)           // (ROWS, DINNER)
{
    __shared__ float sH[4][64], sP[4][64];
    const int tid = threadIdx.x;
    const int c = tid >> 6;            // chunk (== wave id)
    const int w = tid & 63;
    const int dg = (tid >> 4) & 3;
    const int n = tid & 15;
    const int b = blockIdx.x >> 9;
    const int d = ((blockIdx.x & 511) << 2) + dg;
    const int row0 = b * SEQLEN + c * (SEQLEN / 4);

    const float Aa = -__expf(to_f(A_log[d * DSTATE + n]));
    const float Dv = to_f(Dp[d]);

    const float* dp = deltaT + (size_t)d * ROWS + row0;
    const bf16*  up = utT    + (size_t)d * ROWS + row0;
    const bf16*  zp = xzT    + (size_t)(DINNER + d) * ROWS + row0;
    const float* xp = xdbl   + (size_t)row0 * 96;

    // phase 1: local scan + running product
    float h = 0.f, P = 1.f;
    #pragma unroll 4
    for (int i = 0; i < SEQLEN / 4; ++i) {
        float dv = dp[i];
        float uv = to_f(up[i]);
        float Bv = xp[i * 96 + 64 + n];
        float a = __expf(dv * Aa);
        h = fmaf(a, h, dv * Bv * uv);
        P *= a;
    }
    sH[c][w] = h;
    sP[c][w] = P;
    __syncthreads();

    // phase 2: fold preceding chunk summaries
    float hin = 0.f;
    for (int cc = 0; cc < c; ++cc)
        hin = fmaf(sP[cc][w], hin, sH[cc][w]);

    // phase 3: rescan with correct incoming state, fused epilogue
    h = hin;
    #pragma unroll 4
    for (int i = 0; i < SEQLEN / 4; ++i) {
        float dv = dp[i];
        float uv = to_f(up[i]);
        float Bv = xp[i * 96 + 64 + n];
        float Cv = xp[i * 96 + 80 + n];
        float a = __expf(dv * Aa);
        h = fmaf(a, h, dv * Bv * uv);
        float p = h * Cv;
        p += __shfl_xor(p, 1, 16);
        p += __shfl_xor(p, 2, 16);
        p += __shfl_xor(p, 4, 16);
        p += __shfl_xor(p, 8, 16);
        if (n == 0) {
            float z = to_f(zp[i]);
            outz[(size_t)(row0 + i) * DINNER + d] = __float2bfloat16((p + uv * Dv) * silu_f(z));
        }
    }
}

extern "C" void kernel_launch(void* const* d_in, const int* in_sizes, int n_in,
                              void* d_out, int out_size, void* d_ws, size_t ws_size,
                              hipStream_t stream) {
    static const size_t SZ[10] = {
        (size_t)BATCH * SEQLEN * DMODEL,        // hidden_states
        (size_t)2 * DINNER * DMODEL,            // in_proj_w
        (size_t)DINNER * 4,                     // conv1d_w
        (size_t)DINNER,                         // conv1d_b
        (size_t)(DTRANK + 2 * DSTATE) * DINNER, // x_proj_w
        (size_t)DINNER * DTRANK,                // dt_proj_w
        (size_t)DINNER,                         // dt_proj_b
        (size_t)DINNER * DSTATE,                // A_log
        (size_t)DINNER,                         // D_param
        (size_t)DMODEL * DINNER                 // out_proj_w
    };
    size_t tot_in = 0;
    for (int i = 0; i < 10; ++i) tot_in += SZ[i];

    char* p = (char*)d_ws;
    int* flag = (int*)p;                     p += 64;
    bf16* inb = (bf16*)p;                    p += tot_in * 2;
    bf16* xzT = (bf16*)p;                    p += (size_t)4096 * ROWS * 2;
    bf16* utT = (bf16*)p;                    p += (size_t)DINNER * ROWS * 2;
    float* xdbl = (float*)p;                 p += (size_t)ROWS * 96 * 4;
    float* deltaT = (float*)p;               p += (size_t)DINNER * ROWS * 4;
    bf16* outz = (bf16*)p;                   p += (size_t)ROWS * DINNER * 2;
    float* part = (float*)p;                 p += (size_t)2 * ROWS * DMODEL * 4;
    size_t needed = (size_t)(p - (char*)d_ws);
    if (ws_size < needed) return;

    dim3 blk(256);

    detect_kernel<<<1, blk, 0, stream>>>((const unsigned short*)d_in[0], flag);

    bf16* inp[10];
    {
        size_t off = 0;
        for (int i = 0; i < 10; ++i) { inp[i] = inb + off; off += SZ[i]; }
    }
    SrcPtrs sp;
    for (int i = 0; i < 10; ++i) sp.p[i] = d_in[i];
    convert_all<<<(int)((tot_in / 4 + 255) / 256), blk, 0, stream>>>(sp, inb, flag);

    const bf16* hs        = inp[0];
    const bf16* in_proj_w = inp[1];
    const bf16* conv_w    = inp[2];
    const bf16* conv_b    = inp[3];
    const bf16* x_proj_w  = inp[4];
    const bf16* dt_proj_w = inp[5];
    const bf16* dt_proj_b = inp[6];
    const bf16* A_log     = inp[7];
    const bf16* Dp        = inp[8];
    const bf16* out_proj_w= inp[9];

    // 1) xzT = (hs @ in_proj_w^T)^T : M=4096(e) N=2048(row) K=1024  (MFMA, roles swapped)
    gemm_mfma<0><<<dim3(ROWS / 128, 4096 / 128, 1), blk, 0, stream>>>(
        in_proj_w, DMODEL, hs, DMODEL, xzT, ROWS, DMODEL, 0);

    // 2) utT = silu(causal depthwise conv along L) , d-major
    conv_silu_T<<<(DINNER * ROWS) / 256, blk, 0, stream>>>(xzT, conv_w, conv_b, utT);

    // 3) xdbl[row][r] = sum_d utT[d][row] * x_proj_w[r][d]  (gemm_tn, split-K=4)
    zero_f32<<<(ROWS * 96 + 255) / 256, blk, 0, stream>>>(xdbl, ROWS * 96);
    gemm_tn_atomic<<<dim3(2, ROWS / 64, 4), blk, 0, stream>>>(
        utT, ROWS, x_proj_w, DINNER, xdbl, 96, ROWS, 96, DINNER / 4);

    // 4) deltaT[d][row] = softplus(sum_r dtw[d][r]*xdbl[row][r] + dtb[d])  M=d N=row K=64
    gemm_bt<bf16, float, 2><<<dim3(ROWS / 64, DINNER / 64), blk, 0, stream>>>(
        dt_proj_w, DTRANK, xdbl, 96, deltaT, ROWS, DINNER, ROWS, DTRANK, dt_proj_b);

    // 5) chunk-parallel selective scan (coalesced d-major streams) -> outz (row-major)
    scan_kernel4<<<BATCH * (DINNER / 4), blk, 0, stream>>>(
        deltaT, utT, xdbl, xzT, A_log, Dp, outz);

    // 6) out = outz @ out_proj_w^T  M=2048 N=1024 K=2048  (MFMA split-K=2 -> f32 partials)
    gemm_mfma<2><<<dim3(DMODEL / 128, ROWS / 128, 2), blk, 0, stream>>>(
        outz, DINNER, out_proj_w, DINNER, part, DMODEL, DINNER / 2, (size_t)ROWS * DMODEL);

    // 6b) out = cvt(part0 + part1)
    sum_store<<<(ROWS * DMODEL / 4 + 255) / 256, blk, 0, stream>>>(
        part, part + (size_t)ROWS * DMODEL, d_out, flag, ROWS * DMODEL / 4);
}

// Round 7
// 424.924 us; speedup vs baseline: 4.2243x; 1.0673x over previous
//
#include <hip/hip_runtime.h>
#include <hip/hip_bf16.h>

// Shapes: B=2, L=1024, D_MODEL=1024, D_INNER=2048, D_STATE=16, D_CONV=4, DT_RANK=64
#define BATCH 2
#define SEQLEN 1024
#define DMODEL 1024
#define DINNER 2048
#define DSTATE 16
#define DTRANK 64
#define ROWS (BATCH * SEQLEN) // 2048

using bf16 = __hip_bfloat16;
typedef __bf16 bf16x8 __attribute__((ext_vector_type(8)));
typedef float f32x4 __attribute__((ext_vector_type(4)));

__device__ __forceinline__ float to_f(float x) { return x; }
__device__ __forceinline__ float to_f(bf16 x) { return __bfloat162float(x); }

__device__ __forceinline__ float bfu(unsigned short u) {
    union { unsigned int i; float f; } v;
    v.i = ((unsigned int)u) << 16;
    return v.f;
}

__device__ __forceinline__ unsigned short bf_bits(float x) {
    bf16 h = __float2bfloat16(x);
    union { bf16 b; unsigned short u; } cv;
    cv.b = h;
    return cv.u;
}

__device__ __forceinline__ float softplus_f(float x) {
    return fmaxf(x, 0.f) + log1pf(expf(-fabsf(x)));
}
__device__ __forceinline__ float silu_f(float x) {
    return x / (1.f + __expf(-x));
}

// async 16B global -> LDS (wave-uniform base + lane*16 layout)
__device__ __forceinline__ void gload16(const void* g, void* l) {
    __builtin_amdgcn_global_load_lds(
        (const __attribute__((address_space(1))) void*)g,
        (__attribute__((address_space(3))) void*)l, 16, 0, 0);
}

// ---------- dtype detection: bf16 inputs (flag=1) vs f32 inputs (flag=0) ----------
__global__ __launch_bounds__(256) void detect_kernel(const unsigned short* hs, int* flag) {
    __shared__ int cnt[256];
    int c = 0;
    for (int i = threadIdx.x; i < 8192; i += 256) {
        int e = (hs[i] >> 7) & 0xFF;
        if (e == 0 || e == 0xFF || e < 96 || e > 159) c++;
    }
    cnt[threadIdx.x] = c;
    __syncthreads();
    for (int s = 128; s > 0; s >>= 1) {
        if (threadIdx.x < s) cnt[threadIdx.x] += cnt[threadIdx.x + s];
        __syncthreads();
    }
    if (threadIdx.x == 0) *flag = (cnt[0] < 512) ? 1 : 0;
}

// ---------- fused convert of all 10 inputs to one contiguous bf16 arena ----------
struct SrcPtrs { const void* p[10]; };

__device__ __constant__ const size_t SEG_OFF[11] = {
    0, 2097152, 6291456, 6299648, 6301696, 6498304,
    6629376, 6631424, 6664192, 6666240, 8763392
};

__global__ __launch_bounds__(256) void convert_all(SrcPtrs s, bf16* __restrict__ dst,
                                                   const int* __restrict__ flag) {
    size_t e = ((size_t)blockIdx.x * 256 + threadIdx.x) * 4;
    if (e >= SEG_OFF[10]) return;
    int seg = 0;
    #pragma unroll
    for (int i = 1; i < 10; ++i) if (e >= SEG_OFF[i]) seg = i;
    size_t loc = e - SEG_OFF[seg];
    if (*flag) {
        ushort4 v = ((const ushort4*)s.p[seg])[loc / 4];
        ((ushort4*)(dst + e))[0] = v;
    } else {
        float4 v = ((const float4*)s.p[seg])[loc / 4];
        ushort4 o;
        o.x = bf_bits(v.x); o.y = bf_bits(v.y);
        o.z = bf_bits(v.z); o.w = bf_bits(v.w);
        ((ushort4*)(dst + e))[0] = o;
    }
}

__global__ __launch_bounds__(256) void zero_f32(float* p, int n) {
    int i = blockIdx.x * 256 + threadIdx.x;
    if (i < n) p[i] = 0.f;
}

// ---------------- MFMA GEMM: C[m][n] = sum_k A[m][k]*B[n][k], bf16 in, 128x128 tile ----
// OUTMODE: 0 = bf16 store; 2 = f32 store at C + blockIdx.z*pstride (split-K partials)
template <int OUTMODE>
__global__ __launch_bounds__(256) void gemm_mfma(
    const bf16* __restrict__ A, int lda,
    const bf16* __restrict__ Bm, int ldb,
    void* __restrict__ C, int ldc,
    int Kspl, size_t pstride)
{
    __shared__ __align__(16) __bf16 sA[128 * 32];
    __shared__ __align__(16) __bf16 sB[128 * 32];
    const int tid = threadIdx.x;
    const int m0 = blockIdx.y * 128;
    const int n0 = blockIdx.x * 128;
    const int wid = tid >> 6, ln = tid & 63;
    const int wy = (wid >> 1) * 64, wx = (wid & 1) * 64;
    const int q = ln >> 4, m16 = ln & 15;
    const int kbeg = blockIdx.z * Kspl;

    f32x4 acc[4][4] = {};

    for (int k0 = kbeg; k0 < kbeg + Kspl; k0 += 32) {
        #pragma unroll
        for (int i = 0; i < 2; ++i) {
            int idx = tid + i * 256;
            int r = idx >> 2, c = (idx & 3) * 8;
            gload16(&A[(size_t)(m0 + r) * lda + k0 + c], &sA[idx * 8]);
        }
        #pragma unroll
        for (int i = 0; i < 2; ++i) {
            int idx = tid + i * 256;
            int r = idx >> 2, c = (idx & 3) * 8;
            gload16(&Bm[(size_t)(n0 + r) * ldb + k0 + c], &sB[idx * 8]);
        }
        __syncthreads();
        bf16x8 a[4], b[4];
        #pragma unroll
        for (int i = 0; i < 4; ++i)
            a[i] = *(const bf16x8*)&sA[(wy + i * 16 + m16) * 32 + q * 8];
        #pragma unroll
        for (int j = 0; j < 4; ++j)
            b[j] = *(const bf16x8*)&sB[(wx + j * 16 + m16) * 32 + q * 8];
        #pragma unroll
        for (int i = 0; i < 4; ++i)
            #pragma unroll
            for (int j = 0; j < 4; ++j)
                acc[i][j] = __builtin_amdgcn_mfma_f32_16x16x32_bf16(a[i], b[j], acc[i][j], 0, 0, 0);
        __syncthreads();
    }

    #pragma unroll
    for (int i = 0; i < 4; ++i) {
        #pragma unroll
        for (int j = 0; j < 4; ++j) {
            #pragma unroll
            for (int r = 0; r < 4; ++r) {
                int row = m0 + wy + i * 16 + q * 4 + r;
                int col = n0 + wx + j * 16 + m16;
                size_t idx = (size_t)row * ldc + col;
                float v = acc[i][j][r];
                if constexpr (OUTMODE == 0) {
                    ((bf16*)C)[idx] = __float2bfloat16(v);
                } else {
                    ((float*)C + blockIdx.z * pstride)[idx] = v;
                }
            }
        }
    }
}

// sum the two split-K partials, store to d_out as bf16 or f32 per flag
__global__ __launch_bounds__(256) void sum_store(
    const float* __restrict__ p0, const float* __restrict__ p1,
    void* __restrict__ out, const int* __restrict__ flag, int n4)
{
    int i = blockIdx.x * 256 + threadIdx.x;
    if (i >= n4) return;
    float4 a = ((const float4*)p0)[i];
    float4 b = ((const float4*)p1)[i];
    float4 sv; sv.x = a.x + b.x; sv.y = a.y + b.y; sv.z = a.z + b.z; sv.w = a.w + b.w;
    if (*flag) {
        ushort4 o;
        o.x = bf_bits(sv.x); o.y = bf_bits(sv.y);
        o.z = bf_bits(sv.z); o.w = bf_bits(sv.w);
        ((ushort4*)out)[i] = o;
    } else {
        ((float4*)out)[i] = sv;
    }
}

// ---------------- gemm_tn (transposed out): xdT[j][i] = sum_k A[k][i]*B[j][k] ------
// A K-major (utT), B K-contig (x_proj_w). split-K over z, atomicAdd into zeroed C.
__global__ __launch_bounds__(256) void gemm_tn_atomic(
    const bf16* __restrict__ A, int lda,   // A[k][i], lda = ROWS
    const bf16* __restrict__ Bm, int ldb,  // B[j][k]
    float* __restrict__ C, int ldc,        // C[j][i], ldc = ROWS
    int M, int N, int Kspl)
{
    __shared__ float As[16][65];
    __shared__ float Bs[16][65];
    const int tid = threadIdx.x;
    const int tx = tid & 15;
    const int ty = tid >> 4;
    const int i0 = blockIdx.y * 64;
    const int j0 = blockIdx.x * 64;
    const int kbeg = blockIdx.z * Kspl;

    float acc[4][4] = {};

    const int li = tid & 63, lk = tid >> 6;

    for (int k0 = kbeg; k0 < kbeg + Kspl; k0 += 16) {
        #pragma unroll
        for (int it = 0; it < 4; ++it) {
            int k = lk + it * 4;
            As[k][li] = to_f(A[(size_t)(k0 + k) * lda + i0 + li]);
        }
        #pragma unroll
        for (int it = 0; it < 4; ++it) {
            int lin = tid + it * 256;
            int j = lin >> 4, k = lin & 15;
            int gj = j0 + j;
            float v = 0.f;
            if (gj < N) v = to_f(Bm[(size_t)gj * ldb + (k0 + k)]);
            Bs[k][j] = v;
        }
        __syncthreads();
        #pragma unroll
        for (int kk = 0; kk < 16; ++kk) {
            float a[4], b[4];
            #pragma unroll
            for (int i = 0; i < 4; ++i) a[i] = As[kk][ty * 4 + i];
            #pragma unroll
            for (int j = 0; j < 4; ++j) b[j] = Bs[kk][tx * 4 + j];
            #pragma unroll
            for (int i = 0; i < 4; ++i)
                #pragma unroll
                for (int j = 0; j < 4; ++j)
                    acc[i][j] = fmaf(a[i], b[j], acc[i][j]);
        }
        __syncthreads();
    }

    #pragma unroll
    for (int i = 0; i < 4; ++i) {
        int gi = i0 + ty * 4 + i;
        #pragma unroll
        for (int j = 0; j < 4; ++j) {
            int gj = j0 + tx * 4 + j;
            if (gj >= N) continue;
            atomicAdd(&C[(size_t)gj * ldc + gi], acc[i][j]);   // transposed store
        }
    }
}

// ---------------- gemm_nt: C[m][n] = sum_k A[m][k]*B[k][n] ----------------
// A bf16 K-contig (dt_proj_w), B f32 n-contig (xdT rows 0..63).
// EPI: softplus(v + bias[m]). C f32 [m][n], ldc = ROWS. K=64.
__global__ __launch_bounds__(256) void gemm_nt_dt(
    const bf16* __restrict__ A, int lda,
    const float* __restrict__ Bm, int ldb,
    float* __restrict__ C, int ldc,
    int K, const bf16* __restrict__ bias)
{
    __shared__ float As[16][65];
    __shared__ float Bs[16][65];
    const int tid = threadIdx.x;
    const int tx = tid & 15;
    const int ty = tid >> 4;
    const int m0 = blockIdx.y * 64;
    const int n0 = blockIdx.x * 64;

    float acc[4][4] = {};

    for (int k0 = 0; k0 < K; k0 += 16) {
        #pragma unroll
        for (int i = 0; i < 4; ++i) {
            int lin = tid + i * 256;
            int m = lin >> 4, k = lin & 15;
            As[k][m] = to_f(A[(size_t)(m0 + m) * lda + (k0 + k)]);
        }
        #pragma unroll
        for (int it = 0; it < 4; ++it) {
            int k = (tid >> 6) + it * 4;
            int n = tid & 63;
            Bs[k][n] = Bm[(size_t)(k0 + k) * ldb + n0 + n];
        }
        __syncthreads();
        #pragma unroll
        for (int kk = 0; kk < 16; ++kk) {
            float a[4], b[4];
            #pragma unroll
            for (int i = 0; i < 4; ++i) a[i] = As[kk][ty * 4 + i];
            #pragma unroll
            for (int j = 0; j < 4; ++j) b[j] = Bs[kk][tx * 4 + j];
            #pragma unroll
            for (int i = 0; i < 4; ++i)
                #pragma unroll
                for (int j = 0; j < 4; ++j)
                    acc[i][j] = fmaf(a[i], b[j], acc[i][j]);
        }
        __syncthreads();
    }

    #pragma unroll
    for (int i = 0; i < 4; ++i) {
        int gm = m0 + ty * 4 + i;
        float bv = to_f(bias[gm]);
        #pragma unroll
        for (int j = 0; j < 4; ++j) {
            int gn = n0 + tx * 4 + j;
            C[(size_t)gm * ldc + gn] = softplus_f(acc[i][j] + bv);
        }
    }
}

// u^T[d][row] = silu(conv(x^T)+b); x^T = xzT rows 0..2048, row = b*1024+l
__global__ __launch_bounds__(256) void conv_silu_T(
    const bf16* __restrict__ xzT,
    const bf16* __restrict__ w,
    const bf16* __restrict__ bias,
    bf16* __restrict__ utT)
{
    int t = blockIdx.x * 256 + threadIdx.x;   // d*ROWS + row
    int row = t & (ROWS - 1);
    int d = t >> 11;
    int l = row & (SEQLEN - 1);

    const bf16* xp = xzT + (size_t)d * ROWS + row;
    float acc = to_f(bias[d]);
    #pragma unroll
    for (int k = 0; k < 4; ++k) {
        int ll = l - 3 + k;
        if (ll >= 0) acc = fmaf(to_f(xp[k - 3]), to_f(w[d * 4 + k]), acc);
    }
    utT[t] = __float2bfloat16(silu_f(acc));
}

// ---------------- scan v5: chunk-parallel, all streams L-contiguous, 4x vectorized ----
// Block = 256 thr = 4 L-chunks(waves) x 4 d x 16 n; grid = BATCH * DINNER/4 = 1024.
__global__ __launch_bounds__(256) void scan_kernel5(
    const float* __restrict__ deltaT,  // (DINNER, ROWS) f32
    const bf16*  __restrict__ utT,     // (DINNER, ROWS)
    const float* __restrict__ xdT,     // (96, ROWS): row 64+n = B_n, 80+n = C_n
    const bf16*  __restrict__ xzT,     // (4096, ROWS): z at row DINNER+d
    const bf16*  __restrict__ A_log,   // (DINNER,16)
    const bf16*  __restrict__ Dp,      // (DINNER,)
    bf16* __restrict__ outz)           // (ROWS, DINNER)
{
    __shared__ float sH[4][64], sP[4][64];
    const int tid = threadIdx.x;
    const int c = tid >> 6;            // chunk (== wave id)
    const int w = tid & 63;
    const int dg = (tid >> 4) & 3;
    const int n = tid & 15;
    const int b = blockIdx.x >> 9;
    const int d = ((blockIdx.x & 511) << 2) + dg;
    const int row0 = b * SEQLEN + c * (SEQLEN / 4);

    const float Aa = -__expf(to_f(A_log[d * DSTATE + n]));
    const float Dv = to_f(Dp[d]);

    const float*  dp = deltaT + (size_t)d * ROWS + row0;
    const ushort* up = (const ushort*)utT + (size_t)d * ROWS + row0;
    const ushort* zp = (const ushort*)xzT + (size_t)(DINNER + d) * ROWS + row0;
    const float*  Bp = xdT + (size_t)(64 + n) * ROWS + row0;
    const float*  Cp = xdT + (size_t)(80 + n) * ROWS + row0;

    // phase 1: local scan + running product (4-step vectorized)
    float h = 0.f, P = 1.f;
    for (int i0 = 0; i0 < SEQLEN / 4; i0 += 4) {
        float4  dv4 = *(const float4*)(dp + i0);
        ushort4 uv4 = *(const ushort4*)(up + i0);
        float4  Bv4 = *(const float4*)(Bp + i0);
        float dv[4] = {dv4.x, dv4.y, dv4.z, dv4.w};
        float uv[4] = {bfu(uv4.x), bfu(uv4.y), bfu(uv4.z), bfu(uv4.w)};
        float Bv[4] = {Bv4.x, Bv4.y, Bv4.z, Bv4.w};
        #pragma unroll
        for (int j = 0; j < 4; ++j) {
            float a = __expf(dv[j] * Aa);
            h = fmaf(a, h, dv[j] * Bv[j] * uv[j]);
            P *= a;
        }
    }
    sH[c][w] = h;
    sP[c][w] = P;
    __syncthreads();

    // phase 2: fold preceding chunk summaries
    float hin = 0.f;
    for (int cc = 0; cc < c; ++cc)
        hin = fmaf(sP[cc][w], hin, sH[cc][w]);

    // phase 3: rescan with correct incoming state, fused epilogue
    h = hin;
    for (int i0 = 0; i0 < SEQLEN / 4; i0 += 4) {
        float4  dv4 = *(const float4*)(dp + i0);
        ushort4 uv4 = *(const ushort4*)(up + i0);
        float4  Bv4 = *(const float4*)(Bp + i0);
        float4  Cv4 = *(const float4*)(Cp + i0);
        ushort4 zv4 = *(const ushort4*)(zp + i0);
        float dv[4] = {dv4.x, dv4.y, dv4.z, dv4.w};
        float uv[4] = {bfu(uv4.x), bfu(uv4.y), bfu(uv4.z), bfu(uv4.w)};
        float Bv[4] = {Bv4.x, Bv4.y, Bv4.z, Bv4.w};
        float Cv[4] = {Cv4.x, Cv4.y, Cv4.z, Cv4.w};
        float zv[4] = {bfu(zv4.x), bfu(zv4.y), bfu(zv4.z), bfu(zv4.w)};
        #pragma unroll
        for (int j = 0; j < 4; ++j) {
            float a = __expf(dv[j] * Aa);
            h = fmaf(a, h, dv[j] * Bv[j] * uv[j]);
            float p = h * Cv[j];
            p += __shfl_xor(p, 1, 16);
            p += __shfl_xor(p, 2, 16);
            p += __shfl_xor(p, 4, 16);
            p += __shfl_xor(p, 8, 16);
            if (n == 0) {
                outz[(size_t)(row0 + i0 + j) * DINNER + d] =
                    __float2bfloat16((p + uv[j] * Dv) * silu_f(zv[j]));
            }
        }
    }
}

extern "C" void kernel_launch(void* const* d_in, const int* in_sizes, int n_in,
                              void* d_out, int out_size, void* d_ws, size_t ws_size,
                              hipStream_t stream) {
    static const size_t SZ[10] = {
        (size_t)BATCH * SEQLEN * DMODEL,        // hidden_states
        (size_t)2 * DINNER * DMODEL,            // in_proj_w
        (size_t)DINNER * 4,                     // conv1d_w
        (size_t)DINNER,                         // conv1d_b
        (size_t)(DTRANK + 2 * DSTATE) * DINNER, // x_proj_w
        (size_t)DINNER * DTRANK,                // dt_proj_w
        (size_t)DINNER,                         // dt_proj_b
        (size_t)DINNER * DSTATE,                // A_log
        (size_t)DINNER,                         // D_param
        (size_t)DMODEL * DINNER                 // out_proj_w
    };
    size_t tot_in = 0;
    for (int i = 0; i < 10; ++i) tot_in += SZ[i];

    char* p = (char*)d_ws;
    int* flag = (int*)p;                     p += 64;
    bf16* inb = (bf16*)p;                    p += tot_in * 2;
    bf16* xzT = (bf16*)p;                    p += (size_t)4096 * ROWS * 2;
    bf16* utT = (bf16*)p;                    p += (size_t)DINNER * ROWS * 2;
    float* xdT = (float*)p;                  p += (size_t)96 * ROWS * 4;
    float* deltaT = (float*)p;               p += (size_t)DINNER * ROWS * 4;
    bf16* outz = (bf16*)p;                   p += (size_t)ROWS * DINNER * 2;
    float* part = (float*)p;                 p += (size_t)2 * ROWS * DMODEL * 4;
    size_t needed = (size_t)(p - (char*)d_ws);
    if (ws_size < needed) return;

    dim3 blk(256);

    detect_kernel<<<1, blk, 0, stream>>>((const unsigned short*)d_in[0], flag);

    bf16* inp[10];
    {
        size_t off = 0;
        for (int i = 0; i < 10; ++i) { inp[i] = inb + off; off += SZ[i]; }
    }
    SrcPtrs sp;
    for (int i = 0; i < 10; ++i) sp.p[i] = d_in[i];
    convert_all<<<(int)((tot_in / 4 + 255) / 256), blk, 0, stream>>>(sp, inb, flag);

    const bf16* hs        = inp[0];
    const bf16* in_proj_w = inp[1];
    const bf16* conv_w    = inp[2];
    const bf16* conv_b    = inp[3];
    const bf16* x_proj_w  = inp[4];
    const bf16* dt_proj_w = inp[5];
    const bf16* dt_proj_b = inp[6];
    const bf16* A_log     = inp[7];
    const bf16* Dp        = inp[8];
    const bf16* out_proj_w= inp[9];

    // 1) xzT = (hs @ in_proj_w^T)^T : M=4096(e) N=2048(row) K=1024  (MFMA, roles swapped)
    gemm_mfma<0><<<dim3(ROWS / 128, 4096 / 128, 1), blk, 0, stream>>>(
        in_proj_w, DMODEL, hs, DMODEL, xzT, ROWS, DMODEL, 0);

    // 2) utT = silu(causal depthwise conv along L), d-major
    conv_silu_T<<<(DINNER * ROWS) / 256, blk, 0, stream>>>(xzT, conv_w, conv_b, utT);

    // 3) xdT[r][row] = sum_d utT[d][row] * x_proj_w[r][d]  (gemm_tn, transposed out, split-K=4)
    zero_f32<<<(96 * ROWS + 255) / 256, blk, 0, stream>>>(xdT, 96 * ROWS);
    gemm_tn_atomic<<<dim3(2, ROWS / 64, 4), blk, 0, stream>>>(
        utT, ROWS, x_proj_w, DINNER, xdT, ROWS, ROWS, 96, DINNER / 4);

    // 4) deltaT[d][row] = softplus(sum_r dtw[d][r]*xdT[r][row] + dtb[d])
    gemm_nt_dt<<<dim3(ROWS / 64, DINNER / 64), blk, 0, stream>>>(
        dt_proj_w, DTRANK, xdT, ROWS, deltaT, ROWS, DTRANK, dt_proj_b);

    // 5) chunk-parallel selective scan (vectorized L-contiguous streams) -> outz (row-major)
    scan_kernel5<<<BATCH * (DINNER / 4), blk, 0, stream>>>(
        deltaT, utT, xdT, xzT, A_log, Dp, outz);

    // 6) out = outz @ out_proj_w^T  M=2048 N=1024 K=2048  (MFMA split-K=2 -> f32 partials)
    gemm_mfma<2><<<dim3(DMODEL / 128, ROWS / 128, 2), blk, 0, stream>>>(
        outz, DINNER, out_proj_w, DINNER, part, DMODEL, DINNER / 2, (size_t)ROWS * DMODEL);

    // 6b) out = cvt(part0 + part1)
    sum_store<<<(ROWS * DMODEL / 4 + 255) / 256, blk, 0, stream>>>(
        part, part + (size_t)ROWS * DMODEL, d_out, flag, ROWS * DMODEL / 4);
}

// Round 8
// 403.973 us; speedup vs baseline: 4.4434x; 1.0519x over previous
//
#include <hip/hip_runtime.h>
#include <hip/hip_bf16.h>

// Shapes: B=2, L=1024, D_MODEL=1024, D_INNER=2048, D_STATE=16, D_CONV=4, DT_RANK=64
#define BATCH 2
#define SEQLEN 1024
#define DMODEL 1024
#define DINNER 2048
#define DSTATE 16
#define DTRANK 64
#define ROWS (BATCH * SEQLEN) // 2048

using bf16 = __hip_bfloat16;
typedef __bf16 bf16x8 __attribute__((ext_vector_type(8)));
typedef float f32x4 __attribute__((ext_vector_type(4)));

__device__ __forceinline__ float to_f(float x) { return x; }
__device__ __forceinline__ float to_f(bf16 x) { return __bfloat162float(x); }

__device__ __forceinline__ float bfu(unsigned short u) {
    union { unsigned int i; float f; } v;
    v.i = ((unsigned int)u) << 16;
    return v.f;
}

__device__ __forceinline__ unsigned short bf_bits(float x) {
    bf16 h = __float2bfloat16(x);
    union { bf16 b; unsigned short u; } cv;
    cv.b = h;
    return cv.u;
}

__device__ __forceinline__ float softplus_f(float x) {
    return fmaxf(x, 0.f) + log1pf(expf(-fabsf(x)));
}
__device__ __forceinline__ float silu_f(float x) {
    return x / (1.f + __expf(-x));
}

// async 16B global -> LDS (wave-uniform base + lane*16 layout)
__device__ __forceinline__ void gload16(const void* g, void* l) {
    __builtin_amdgcn_global_load_lds(
        (const __attribute__((address_space(1))) void*)g,
        (__attribute__((address_space(3))) void*)l, 16, 0, 0);
}

// ---------- dtype detection: bf16 inputs (flag=1) vs f32 inputs (flag=0) ----------
__global__ __launch_bounds__(256) void detect_kernel(const unsigned short* hs, int* flag) {
    __shared__ int cnt[256];
    int c = 0;
    for (int i = threadIdx.x; i < 8192; i += 256) {
        int e = (hs[i] >> 7) & 0xFF;
        if (e == 0 || e == 0xFF || e < 96 || e > 159) c++;
    }
    cnt[threadIdx.x] = c;
    __syncthreads();
    for (int s = 128; s > 0; s >>= 1) {
        if (threadIdx.x < s) cnt[threadIdx.x] += cnt[threadIdx.x + s];
        __syncthreads();
    }
    if (threadIdx.x == 0) *flag = (cnt[0] < 512) ? 1 : 0;
}

// ---------- fused convert of all 10 inputs to one contiguous bf16 arena ----------
struct SrcPtrs { const void* p[10]; };

__device__ __constant__ const size_t SEG_OFF[11] = {
    0, 2097152, 6291456, 6299648, 6301696, 6498304,
    6629376, 6631424, 6664192, 6666240, 8763392
};

__global__ __launch_bounds__(256) void convert_all(SrcPtrs s, bf16* __restrict__ dst,
                                                   const int* __restrict__ flag) {
    size_t e = ((size_t)blockIdx.x * 256 + threadIdx.x) * 4;
    if (e >= SEG_OFF[10]) return;
    int seg = 0;
    #pragma unroll
    for (int i = 1; i < 10; ++i) if (e >= SEG_OFF[i]) seg = i;
    size_t loc = e - SEG_OFF[seg];
    if (*flag) {
        ushort4 v = ((const ushort4*)s.p[seg])[loc / 4];
        ((ushort4*)(dst + e))[0] = v;
    } else {
        float4 v = ((const float4*)s.p[seg])[loc / 4];
        ushort4 o;
        o.x = bf_bits(v.x); o.y = bf_bits(v.y);
        o.z = bf_bits(v.z); o.w = bf_bits(v.w);
        ((ushort4*)(dst + e))[0] = o;
    }
}

__global__ __launch_bounds__(256) void zero_f32(float* p, int n) {
    int i = blockIdx.x * 256 + threadIdx.x;
    if (i < n) p[i] = 0.f;
}

// ---------------- MFMA GEMM: C[m][n] = sum_k A[m][k]*B[n][k], bf16 in, 128x128 tile ----
// OUTMODE: 0 = bf16 store; 2 = f32 store at C + blockIdx.z*pstride (split-K partials)
template <int OUTMODE>
__global__ __launch_bounds__(256) void gemm_mfma(
    const bf16* __restrict__ A, int lda,
    const bf16* __restrict__ Bm, int ldb,
    void* __restrict__ C, int ldc,
    int Kspl, size_t pstride)
{
    __shared__ __align__(16) __bf16 sA[128 * 32];
    __shared__ __align__(16) __bf16 sB[128 * 32];
    const int tid = threadIdx.x;
    const int m0 = blockIdx.y * 128;
    const int n0 = blockIdx.x * 128;
    const int wid = tid >> 6, ln = tid & 63;
    const int wy = (wid >> 1) * 64, wx = (wid & 1) * 64;
    const int q = ln >> 4, m16 = ln & 15;
    const int kbeg = blockIdx.z * Kspl;

    f32x4 acc[4][4] = {};

    for (int k0 = kbeg; k0 < kbeg + Kspl; k0 += 32) {
        #pragma unroll
        for (int i = 0; i < 2; ++i) {
            int idx = tid + i * 256;
            int r = idx >> 2, c = (idx & 3) * 8;
            gload16(&A[(size_t)(m0 + r) * lda + k0 + c], &sA[idx * 8]);
        }
        #pragma unroll
        for (int i = 0; i < 2; ++i) {
            int idx = tid + i * 256;
            int r = idx >> 2, c = (idx & 3) * 8;
            gload16(&Bm[(size_t)(n0 + r) * ldb + k0 + c], &sB[idx * 8]);
        }
        __syncthreads();
        bf16x8 a[4], b[4];
        #pragma unroll
        for (int i = 0; i < 4; ++i)
            a[i] = *(const bf16x8*)&sA[(wy + i * 16 + m16) * 32 + q * 8];
        #pragma unroll
        for (int j = 0; j < 4; ++j)
            b[j] = *(const bf16x8*)&sB[(wx + j * 16 + m16) * 32 + q * 8];
        #pragma unroll
        for (int i = 0; i < 4; ++i)
            #pragma unroll
            for (int j = 0; j < 4; ++j)
                acc[i][j] = __builtin_amdgcn_mfma_f32_16x16x32_bf16(a[i], b[j], acc[i][j], 0, 0, 0);
        __syncthreads();
    }

    #pragma unroll
    for (int i = 0; i < 4; ++i) {
        #pragma unroll
        for (int j = 0; j < 4; ++j) {
            #pragma unroll
            for (int r = 0; r < 4; ++r) {
                int row = m0 + wy + i * 16 + q * 4 + r;
                int col = n0 + wx + j * 16 + m16;
                size_t idx = (size_t)row * ldc + col;
                float v = acc[i][j][r];
                if constexpr (OUTMODE == 0) {
                    ((bf16*)C)[idx] = __float2bfloat16(v);
                } else {
                    ((float*)C + blockIdx.z * pstride)[idx] = v;
                }
            }
        }
    }
}

// sum the two split-K partials, store to d_out as bf16 or f32 per flag
__global__ __launch_bounds__(256) void sum_store(
    const float* __restrict__ p0, const float* __restrict__ p1,
    void* __restrict__ out, const int* __restrict__ flag, int n4)
{
    int i = blockIdx.x * 256 + threadIdx.x;
    if (i >= n4) return;
    float4 a = ((const float4*)p0)[i];
    float4 b = ((const float4*)p1)[i];
    float4 sv; sv.x = a.x + b.x; sv.y = a.y + b.y; sv.z = a.z + b.z; sv.w = a.w + b.w;
    if (*flag) {
        ushort4 o;
        o.x = bf_bits(sv.x); o.y = bf_bits(sv.y);
        o.z = bf_bits(sv.z); o.w = bf_bits(sv.w);
        ((ushort4*)out)[i] = o;
    } else {
        ((float4*)out)[i] = sv;
    }
}

// ---------------- gemm_tn (transposed out): xdT[j][i] = sum_k A[k][i]*B[j][k] ------
// A K-major (utT), B K-contig (x_proj_w). split-K over z, atomicAdd into zeroed C.
__global__ __launch_bounds__(256) void gemm_tn_atomic(
    const bf16* __restrict__ A, int lda,   // A[k][i], lda = ROWS
    const bf16* __restrict__ Bm, int ldb,  // B[j][k]
    float* __restrict__ C, int ldc,        // C[j][i], ldc = ROWS
    int M, int N, int Kspl)
{
    __shared__ float As[16][65];
    __shared__ float Bs[16][65];
    const int tid = threadIdx.x;
    const int tx = tid & 15;
    const int ty = tid >> 4;
    const int i0 = blockIdx.y * 64;
    const int j0 = blockIdx.x * 64;
    const int kbeg = blockIdx.z * Kspl;

    float acc[4][4] = {};

    const int li = tid & 63, lk = tid >> 6;

    for (int k0 = kbeg; k0 < kbeg + Kspl; k0 += 16) {
        #pragma unroll
        for (int it = 0; it < 4; ++it) {
            int k = lk + it * 4;
            As[k][li] = to_f(A[(size_t)(k0 + k) * lda + i0 + li]);
        }
        #pragma unroll
        for (int it = 0; it < 4; ++it) {
            int lin = tid + it * 256;
            int j = lin >> 4, k = lin & 15;
            int gj = j0 + j;
            float v = 0.f;
            if (gj < N) v = to_f(Bm[(size_t)gj * ldb + (k0 + k)]);
            Bs[k][j] = v;
        }
        __syncthreads();
        #pragma unroll
        for (int kk = 0; kk < 16; ++kk) {
            float a[4], b[4];
            #pragma unroll
            for (int i = 0; i < 4; ++i) a[i] = As[kk][ty * 4 + i];
            #pragma unroll
            for (int j = 0; j < 4; ++j) b[j] = Bs[kk][tx * 4 + j];
            #pragma unroll
            for (int i = 0; i < 4; ++i)
                #pragma unroll
                for (int j = 0; j < 4; ++j)
                    acc[i][j] = fmaf(a[i], b[j], acc[i][j]);
        }
        __syncthreads();
    }

    #pragma unroll
    for (int i = 0; i < 4; ++i) {
        int gi = i0 + ty * 4 + i;
        #pragma unroll
        for (int j = 0; j < 4; ++j) {
            int gj = j0 + tx * 4 + j;
            if (gj >= N) continue;
            atomicAdd(&C[(size_t)gj * ldc + gi], acc[i][j]);   // transposed store
        }
    }
}

// ---------------- gemm_nt: C[m][n] = sum_k A[m][k]*B[k][n] ----------------
// A bf16 K-contig (dt_proj_w), B f32 n-contig (xdT rows 0..63).
// EPI: softplus(v + bias[m]). C f32 [m][n], ldc = ROWS. K=64.
__global__ __launch_bounds__(256) void gemm_nt_dt(
    const bf16* __restrict__ A, int lda,
    const float* __restrict__ Bm, int ldb,
    float* __restrict__ C, int ldc,
    int K, const bf16* __restrict__ bias)
{
    __shared__ float As[16][65];
    __shared__ float Bs[16][65];
    const int tid = threadIdx.x;
    const int tx = tid & 15;
    const int ty = tid >> 4;
    const int m0 = blockIdx.y * 64;
    const int n0 = blockIdx.x * 64;

    float acc[4][4] = {};

    for (int k0 = 0; k0 < K; k0 += 16) {
        #pragma unroll
        for (int i = 0; i < 4; ++i) {
            int lin = tid + i * 256;
            int m = lin >> 4, k = lin & 15;
            As[k][m] = to_f(A[(size_t)(m0 + m) * lda + (k0 + k)]);
        }
        #pragma unroll
        for (int it = 0; it < 4; ++it) {
            int k = (tid >> 6) + it * 4;
            int n = tid & 63;
            Bs[k][n] = Bm[(size_t)(k0 + k) * ldb + n0 + n];
        }
        __syncthreads();
        #pragma unroll
        for (int kk = 0; kk < 16; ++kk) {
            float a[4], b[4];
            #pragma unroll
            for (int i = 0; i < 4; ++i) a[i] = As[kk][ty * 4 + i];
            #pragma unroll
            for (int j = 0; j < 4; ++j) b[j] = Bs[kk][tx * 4 + j];
            #pragma unroll
            for (int i = 0; i < 4; ++i)
                #pragma unroll
                for (int j = 0; j < 4; ++j)
                    acc[i][j] = fmaf(a[i], b[j], acc[i][j]);
        }
        __syncthreads();
    }

    #pragma unroll
    for (int i = 0; i < 4; ++i) {
        int gm = m0 + ty * 4 + i;
        float bv = to_f(bias[gm]);
        #pragma unroll
        for (int j = 0; j < 4; ++j) {
            int gn = n0 + tx * 4 + j;
            C[(size_t)gm * ldc + gn] = softplus_f(acc[i][j] + bv);
        }
    }
}

// u^T[d][row] = silu(conv(x^T)+b); x^T = xzT rows 0..2048, row = b*1024+l
__global__ __launch_bounds__(256) void conv_silu_T(
    const bf16* __restrict__ xzT,
    const bf16* __restrict__ w,
    const bf16* __restrict__ bias,
    bf16* __restrict__ utT)
{
    int t = blockIdx.x * 256 + threadIdx.x;   // d*ROWS + row
    int row = t & (ROWS - 1);
    int d = t >> 11;
    int l = row & (SEQLEN - 1);

    const bf16* xp = xzT + (size_t)d * ROWS + row;
    float acc = to_f(bias[d]);
    #pragma unroll
    for (int k = 0; k < 4; ++k) {
        int ll = l - 3 + k;
        if (ll >= 0) acc = fmaf(to_f(xp[k - 3]), to_f(w[d * 4 + k]), acc);
    }
    utT[t] = __float2bfloat16(silu_f(acc));
}

// ---------------- scan v6: 16 chunks of 64 steps, 1024-thread blocks ----------
// Block = 1024 thr = 16 L-chunks(waves) x 4 d x 16 n; grid = BATCH * DINNER/4 = 1024.
// 2 blocks/CU = 32 waves/CU (max occupancy); serial chain = 64 steps per phase.
#define SCHUNK 16
#define SSTEPS (SEQLEN / SCHUNK)   // 64
__global__ __launch_bounds__(1024) void scan_kernel6(
    const float* __restrict__ deltaT,  // (DINNER, ROWS) f32
    const bf16*  __restrict__ utT,     // (DINNER, ROWS)
    const float* __restrict__ xdT,     // (96, ROWS): row 64+n = B_n, 80+n = C_n
    const bf16*  __restrict__ xzT,     // (4096, ROWS): z at row DINNER+d
    const bf16*  __restrict__ A_log,   // (DINNER,16)
    const bf16*  __restrict__ Dp,      // (DINNER,)
    bf16* __restrict__ outz)           // (ROWS, DINNER)
{
    __shared__ float sH[SCHUNK][64], sP[SCHUNK][64];
    const int tid = threadIdx.x;
    const int c = tid >> 6;            // chunk (== wave id), 0..15
    const int w = tid & 63;
    const int dg = (tid >> 4) & 3;
    const int n = tid & 15;
    const int b = blockIdx.x >> 9;
    const int d = ((blockIdx.x & 511) << 2) + dg;
    const int row0 = b * SEQLEN + c * SSTEPS;

    const float Aa = -__expf(to_f(A_log[d * DSTATE + n]));
    const float Dv = to_f(Dp[d]);

    const float*  dp = deltaT + (size_t)d * ROWS + row0;
    const ushort* up = (const ushort*)utT + (size_t)d * ROWS + row0;
    const ushort* zp = (const ushort*)xzT + (size_t)(DINNER + d) * ROWS + row0;
    const float*  Bp = xdT + (size_t)(64 + n) * ROWS + row0;
    const float*  Cp = xdT + (size_t)(80 + n) * ROWS + row0;

    // phase 1: local scan + running product (4-step vectorized)
    float h = 0.f, P = 1.f;
    for (int i0 = 0; i0 < SSTEPS; i0 += 4) {
        float4  dv4 = *(const float4*)(dp + i0);
        ushort4 uv4 = *(const ushort4*)(up + i0);
        float4  Bv4 = *(const float4*)(Bp + i0);
        float dv[4] = {dv4.x, dv4.y, dv4.z, dv4.w};
        float uv[4] = {bfu(uv4.x), bfu(uv4.y), bfu(uv4.z), bfu(uv4.w)};
        float Bv[4] = {Bv4.x, Bv4.y, Bv4.z, Bv4.w};
        #pragma unroll
        for (int j = 0; j < 4; ++j) {
            float a = __expf(dv[j] * Aa);
            h = fmaf(a, h, dv[j] * Bv[j] * uv[j]);
            P *= a;
        }
    }
    sH[c][w] = h;
    sP[c][w] = P;
    __syncthreads();

    // phase 2: fold preceding chunk summaries (<=15 fma, wave-uniform)
    float hin = 0.f;
    for (int cc = 0; cc < c; ++cc)
        hin = fmaf(sP[cc][w], hin, sH[cc][w]);

    // phase 3: rescan with correct incoming state, fused epilogue
    h = hin;
    for (int i0 = 0; i0 < SSTEPS; i0 += 4) {
        float4  dv4 = *(const float4*)(dp + i0);
        ushort4 uv4 = *(const ushort4*)(up + i0);
        float4  Bv4 = *(const float4*)(Bp + i0);
        float4  Cv4 = *(const float4*)(Cp + i0);
        ushort4 zv4 = *(const ushort4*)(zp + i0);
        float dv[4] = {dv4.x, dv4.y, dv4.z, dv4.w};
        float uv[4] = {bfu(uv4.x), bfu(uv4.y), bfu(uv4.z), bfu(uv4.w)};
        float Bv[4] = {Bv4.x, Bv4.y, Bv4.z, Bv4.w};
        float Cv[4] = {Cv4.x, Cv4.y, Cv4.z, Cv4.w};
        float zv[4] = {bfu(zv4.x), bfu(zv4.y), bfu(zv4.z), bfu(zv4.w)};
        #pragma unroll
        for (int j = 0; j < 4; ++j) {
            float a = __expf(dv[j] * Aa);
            h = fmaf(a, h, dv[j] * Bv[j] * uv[j]);
            float p = h * Cv[j];
            p += __shfl_xor(p, 1, 16);
            p += __shfl_xor(p, 2, 16);
            p += __shfl_xor(p, 4, 16);
            p += __shfl_xor(p, 8, 16);
            if (n == 0) {
                outz[(size_t)(row0 + i0 + j) * DINNER + d] =
                    __float2bfloat16((p + uv[j] * Dv) * silu_f(zv[j]));
            }
        }
    }
}

extern "C" void kernel_launch(void* const* d_in, const int* in_sizes, int n_in,
                              void* d_out, int out_size, void* d_ws, size_t ws_size,
                              hipStream_t stream) {
    static const size_t SZ[10] = {
        (size_t)BATCH * SEQLEN * DMODEL,        // hidden_states
        (size_t)2 * DINNER * DMODEL,            // in_proj_w
        (size_t)DINNER * 4,                     // conv1d_w
        (size_t)DINNER,                         // conv1d_b
        (size_t)(DTRANK + 2 * DSTATE) * DINNER, // x_proj_w
        (size_t)DINNER * DTRANK,                // dt_proj_w
        (size_t)DINNER,                         // dt_proj_b
        (size_t)DINNER * DSTATE,                // A_log
        (size_t)DINNER,                         // D_param
        (size_t)DMODEL * DINNER                 // out_proj_w
    };
    size_t tot_in = 0;
    for (int i = 0; i < 10; ++i) tot_in += SZ[i];

    char* p = (char*)d_ws;
    int* flag = (int*)p;                     p += 64;
    bf16* inb = (bf16*)p;                    p += tot_in * 2;
    bf16* xzT = (bf16*)p;                    p += (size_t)4096 * ROWS * 2;
    bf16* utT = (bf16*)p;                    p += (size_t)DINNER * ROWS * 2;
    float* xdT = (float*)p;                  p += (size_t)96 * ROWS * 4;
    float* deltaT = (float*)p;               p += (size_t)DINNER * ROWS * 4;
    bf16* outz = (bf16*)p;                   p += (size_t)ROWS * DINNER * 2;
    float* part = (float*)p;                 p += (size_t)2 * ROWS * DMODEL * 4;
    size_t needed = (size_t)(p - (char*)d_ws);
    if (ws_size < needed) return;

    dim3 blk(256);

    detect_kernel<<<1, blk, 0, stream>>>((const unsigned short*)d_in[0], flag);

    bf16* inp[10];
    {
        size_t off = 0;
        for (int i = 0; i < 10; ++i) { inp[i] = inb + off; off += SZ[i]; }
    }
    SrcPtrs sp;
    for (int i = 0; i < 10; ++i) sp.p[i] = d_in[i];
    convert_all<<<(int)((tot_in / 4 + 255) / 256), blk, 0, stream>>>(sp, inb, flag);

    const bf16* hs        = inp[0];
    const bf16* in_proj_w = inp[1];
    const bf16* conv_w    = inp[2];
    const bf16* conv_b    = inp[3];
    const bf16* x_proj_w  = inp[4];
    const bf16* dt_proj_w = inp[5];
    const bf16* dt_proj_b = inp[6];
    const bf16* A_log     = inp[7];
    const bf16* Dp        = inp[8];
    const bf16* out_proj_w= inp[9];

    // 1) xzT = (hs @ in_proj_w^T)^T : M=4096(e) N=2048(row) K=1024  (MFMA, roles swapped)
    gemm_mfma<0><<<dim3(ROWS / 128, 4096 / 128, 1), blk, 0, stream>>>(
        in_proj_w, DMODEL, hs, DMODEL, xzT, ROWS, DMODEL, 0);

    // 2) utT = silu(causal depthwise conv along L), d-major
    conv_silu_T<<<(DINNER * ROWS) / 256, blk, 0, stream>>>(xzT, conv_w, conv_b, utT);

    // 3) xdT[r][row] = sum_d utT[d][row] * x_proj_w[r][d]  (gemm_tn, transposed out, split-K=4)
    zero_f32<<<(96 * ROWS + 255) / 256, blk, 0, stream>>>(xdT, 96 * ROWS);
    gemm_tn_atomic<<<dim3(2, ROWS / 64, 4), blk, 0, stream>>>(
        utT, ROWS, x_proj_w, DINNER, xdT, ROWS, ROWS, 96, DINNER / 4);

    // 4) deltaT[d][row] = softplus(sum_r dtw[d][r]*xdT[r][row] + dtb[d])
    gemm_nt_dt<<<dim3(ROWS / 64, DINNER / 64), blk, 0, stream>>>(
        dt_proj_w, DTRANK, xdT, ROWS, deltaT, ROWS, DTRANK, dt_proj_b);

    // 5) chunk-parallel selective scan (16 chunks, 1024-thr blocks) -> outz (row-major)
    scan_kernel6<<<BATCH * (DINNER / 4), dim3(1024), 0, stream>>>(
        deltaT, utT, xdT, xzT, A_log, Dp, outz);

    // 6) out = outz @ out_proj_w^T  M=2048 N=1024 K=2048  (MFMA split-K=2 -> f32 partials)
    gemm_mfma<2><<<dim3(DMODEL / 128, ROWS / 128, 2), blk, 0, stream>>>(
        outz, DINNER, out_proj_w, DINNER, part, DMODEL, DINNER / 2, (size_t)ROWS * DMODEL);

    // 6b) out = cvt(part0 + part1)
    sum_store<<<(ROWS * DMODEL / 4 + 255) / 256, blk, 0, stream>>>(
        part, part + (size_t)ROWS * DMODEL, d_out, flag, ROWS * DMODEL / 4);
}

// Round 10
// 378.177 us; speedup vs baseline: 4.7465x; 1.0682x over previous
//
#include <hip/hip_runtime.h>
#include <hip/hip_bf16.h>

// Shapes: B=2, L=1024, D_MODEL=1024, D_INNER=2048, D_STATE=16, D_CONV=4, DT_RANK=64
#define BATCH 2
#define SEQLEN 1024
#define DMODEL 1024
#define DINNER 2048
#define DSTATE 16
#define DTRANK 64
#define ROWS (BATCH * SEQLEN) // 2048
#define LOG2E 1.44269504088896340736f

using bf16 = __hip_bfloat16;
typedef __bf16 bf16x8 __attribute__((ext_vector_type(8)));
typedef float f32x4 __attribute__((ext_vector_type(4)));
typedef unsigned short us8 __attribute__((ext_vector_type(8)));

__device__ __forceinline__ float to_f(float x) { return x; }
__device__ __forceinline__ float to_f(bf16 x) { return __bfloat162float(x); }

__device__ __forceinline__ float fexp2(float x) { return __builtin_amdgcn_exp2f(x); }

__device__ __forceinline__ float bfu(unsigned short u) {
    union { unsigned int i; float f; } v;
    v.i = ((unsigned int)u) << 16;
    return v.f;
}

__device__ __forceinline__ unsigned short bf_bits(float x) {
    bf16 h = __float2bfloat16(x);
    union { bf16 b; unsigned short u; } cv;
    cv.b = h;
    return cv.u;
}

__device__ __forceinline__ float softplus_f(float x) {
    return fmaxf(x, 0.f) + log1pf(expf(-fabsf(x)));
}
// fast silu: z * rcp(1 + exp2(-z*log2e))
__device__ __forceinline__ float silu_f(float x) {
    return x * __builtin_amdgcn_rcpf(1.f + fexp2(-x * LOG2E));
}

// async 16B global -> LDS (wave-uniform base + lane*16 layout)
__device__ __forceinline__ void gload16(const void* g, void* l) {
    __builtin_amdgcn_global_load_lds(
        (const __attribute__((address_space(1))) void*)g,
        (__attribute__((address_space(3))) void*)l, 16, 0, 0);
}

// ---------- prep: block 0 = dtype detect; blocks 1.. zero xdT ----------
__global__ __launch_bounds__(256) void prep_kernel(const unsigned short* hs, int* flag,
                                                   float* zbuf, int nzero) {
    if (blockIdx.x == 0) {
        __shared__ int cnt[256];
        int c = 0;
        for (int i = threadIdx.x; i < 8192; i += 256) {
            int e = (hs[i] >> 7) & 0xFF;
            if (e == 0 || e == 0xFF || e < 96 || e > 159) c++;
        }
        cnt[threadIdx.x] = c;
        __syncthreads();
        for (int s = 128; s > 0; s >>= 1) {
            if (threadIdx.x < s) cnt[threadIdx.x] += cnt[threadIdx.x + s];
            __syncthreads();
        }
        if (threadIdx.x == 0) *flag = (cnt[0] < 512) ? 1 : 0;
    } else {
        int i = (blockIdx.x - 1) * 256 + threadIdx.x;
        if (i < nzero) zbuf[i] = 0.f;
    }
}

// ---------- fused convert of all 10 inputs to one contiguous bf16 arena ----------
struct SrcPtrs { const void* p[10]; };

__device__ __constant__ const size_t SEG_OFF[11] = {
    0, 2097152, 6291456, 6299648, 6301696, 6498304,
    6629376, 6631424, 6664192, 6666240, 8763392
};

__global__ __launch_bounds__(256) void convert_all(SrcPtrs s, bf16* __restrict__ dst,
                                                   const int* __restrict__ flag) {
    size_t e = ((size_t)blockIdx.x * 256 + threadIdx.x) * 4;
    if (e >= SEG_OFF[10]) return;
    int seg = 0;
    #pragma unroll
    for (int i = 1; i < 10; ++i) if (e >= SEG_OFF[i]) seg = i;
    size_t loc = e - SEG_OFF[seg];
    if (*flag) {
        ushort4 v = ((const ushort4*)s.p[seg])[loc / 4];
        ((ushort4*)(dst + e))[0] = v;
    } else {
        float4 v = ((const float4*)s.p[seg])[loc / 4];
        ushort4 o;
        o.x = bf_bits(v.x); o.y = bf_bits(v.y);
        o.z = bf_bits(v.z); o.w = bf_bits(v.w);
        ((ushort4*)(dst + e))[0] = o;
    }
}

// ---------------- MFMA GEMM: C[m][n] = sum_k A[m][k]*B[n][k], bf16 in, 128x128 tile ----
// OUTMODE: 0 = bf16 store; 2 = f32 store at C + blockIdx.z*pstride (split-K partials)
template <int OUTMODE>
__global__ __launch_bounds__(256) void gemm_mfma(
    const bf16* __restrict__ A, int lda,
    const bf16* __restrict__ Bm, int ldb,
    void* __restrict__ C, int ldc,
    int Kspl, size_t pstride)
{
    __shared__ __align__(16) __bf16 sA[128 * 32];
    __shared__ __align__(16) __bf16 sB[128 * 32];
    const int tid = threadIdx.x;
    const int m0 = blockIdx.y * 128;
    const int n0 = blockIdx.x * 128;
    const int wid = tid >> 6, ln = tid & 63;
    const int wy = (wid >> 1) * 64, wx = (wid & 1) * 64;
    const int q = ln >> 4, m16 = ln & 15;
    const int kbeg = blockIdx.z * Kspl;

    f32x4 acc[4][4] = {};

    for (int k0 = kbeg; k0 < kbeg + Kspl; k0 += 32) {
        #pragma unroll
        for (int i = 0; i < 2; ++i) {
            int idx = tid + i * 256;
            int r = idx >> 2, c = (idx & 3) * 8;
            gload16(&A[(size_t)(m0 + r) * lda + k0 + c], &sA[idx * 8]);
        }
        #pragma unroll
        for (int i = 0; i < 2; ++i) {
            int idx = tid + i * 256;
            int r = idx >> 2, c = (idx & 3) * 8;
            gload16(&Bm[(size_t)(n0 + r) * ldb + k0 + c], &sB[idx * 8]);
        }
        __syncthreads();
        bf16x8 a[4], b[4];
        #pragma unroll
        for (int i = 0; i < 4; ++i)
            a[i] = *(const bf16x8*)&sA[(wy + i * 16 + m16) * 32 + q * 8];
        #pragma unroll
        for (int j = 0; j < 4; ++j)
            b[j] = *(const bf16x8*)&sB[(wx + j * 16 + m16) * 32 + q * 8];
        #pragma unroll
        for (int i = 0; i < 4; ++i)
            #pragma unroll
            for (int j = 0; j < 4; ++j)
                acc[i][j] = __builtin_amdgcn_mfma_f32_16x16x32_bf16(a[i], b[j], acc[i][j], 0, 0, 0);
        __syncthreads();
    }

    #pragma unroll
    for (int i = 0; i < 4; ++i) {
        #pragma unroll
        for (int j = 0; j < 4; ++j) {
            #pragma unroll
            for (int r = 0; r < 4; ++r) {
                int row = m0 + wy + i * 16 + q * 4 + r;
                int col = n0 + wx + j * 16 + m16;
                size_t idx = (size_t)row * ldc + col;
                float v = acc[i][j][r];
                if constexpr (OUTMODE == 0) {
                    ((bf16*)C)[idx] = __float2bfloat16(v);
                } else {
                    ((float*)C + blockIdx.z * pstride)[idx] = v;
                }
            }
        }
    }
}

// sum the two split-K partials, store to d_out as bf16 or f32 per flag
__global__ __launch_bounds__(256) void sum_store(
    const float* __restrict__ p0, const float* __restrict__ p1,
    void* __restrict__ out, const int* __restrict__ flag, int n4)
{
    int i = blockIdx.x * 256 + threadIdx.x;
    if (i >= n4) return;
    float4 a = ((const float4*)p0)[i];
    float4 b = ((const float4*)p1)[i];
    float4 sv; sv.x = a.x + b.x; sv.y = a.y + b.y; sv.z = a.z + b.z; sv.w = a.w + b.w;
    if (*flag) {
        ushort4 o;
        o.x = bf_bits(sv.x); o.y = bf_bits(sv.y);
        o.z = bf_bits(sv.z); o.w = bf_bits(sv.w);
        ((ushort4*)out)[i] = o;
    } else {
        ((float4*)out)[i] = sv;
    }
}

// ---------------- gemm_tn (transposed out): xdT[j][i] = sum_k A[k][i]*B[j][k] ------
__global__ __launch_bounds__(256) void gemm_tn_atomic(
    const bf16* __restrict__ A, int lda,   // A[k][i], lda = ROWS
    const bf16* __restrict__ Bm, int ldb,  // B[j][k]
    float* __restrict__ C, int ldc,        // C[j][i], ldc = ROWS
    int M, int N, int Kspl)
{
    __shared__ float As[16][65];
    __shared__ float Bs[16][65];
    const int tid = threadIdx.x;
    const int tx = tid & 15;
    const int ty = tid >> 4;
    const int i0 = blockIdx.y * 64;
    const int j0 = blockIdx.x * 64;
    const int kbeg = blockIdx.z * Kspl;

    float acc[4][4] = {};

    const int li = tid & 63, lk = tid >> 6;

    for (int k0 = kbeg; k0 < kbeg + Kspl; k0 += 16) {
        #pragma unroll
        for (int it = 0; it < 4; ++it) {
            int k = lk + it * 4;
            As[k][li] = to_f(A[(size_t)(k0 + k) * lda + i0 + li]);
        }
        #pragma unroll
        for (int it = 0; it < 4; ++it) {
            int lin = tid + it * 256;
            int j = lin >> 4, k = lin & 15;
            int gj = j0 + j;
            float v = 0.f;
            if (gj < N) v = to_f(Bm[(size_t)gj * ldb + (k0 + k)]);
            Bs[k][j] = v;
        }
        __syncthreads();
        #pragma unroll
        for (int kk = 0; kk < 16; ++kk) {
            float a[4], b[4];
            #pragma unroll
            for (int i = 0; i < 4; ++i) a[i] = As[kk][ty * 4 + i];
            #pragma unroll
            for (int j = 0; j < 4; ++j) b[j] = Bs[kk][tx * 4 + j];
            #pragma unroll
            for (int i = 0; i < 4; ++i)
                #pragma unroll
                for (int j = 0; j < 4; ++j)
                    acc[i][j] = fmaf(a[i], b[j], acc[i][j]);
        }
        __syncthreads();
    }

    #pragma unroll
    for (int i = 0; i < 4; ++i) {
        int gi = i0 + ty * 4 + i;
        #pragma unroll
        for (int j = 0; j < 4; ++j) {
            int gj = j0 + tx * 4 + j;
            if (gj >= N) continue;
            atomicAdd(&C[(size_t)gj * ldc + gi], acc[i][j]);   // transposed store
        }
    }
}

// ---------------- gemm_nt: deltaT[m][n] = softplus(sum_k A[m][k]*B[k][n] + bias[m]) ----
__global__ __launch_bounds__(256) void gemm_nt_dt(
    const bf16* __restrict__ A, int lda,
    const float* __restrict__ Bm, int ldb,
    float* __restrict__ C, int ldc,
    int K, const bf16* __restrict__ bias)
{
    __shared__ float As[16][65];
    __shared__ float Bs[16][65];
    const int tid = threadIdx.x;
    const int tx = tid & 15;
    const int ty = tid >> 4;
    const int m0 = blockIdx.y * 64;
    const int n0 = blockIdx.x * 64;

    float acc[4][4] = {};

    for (int k0 = 0; k0 < K; k0 += 16) {
        #pragma unroll
        for (int i = 0; i < 4; ++i) {
            int lin = tid + i * 256;
            int m = lin >> 4, k = lin & 15;
            As[k][m] = to_f(A[(size_t)(m0 + m) * lda + (k0 + k)]);
        }
        #pragma unroll
        for (int it = 0; it < 4; ++it) {
            int k = (tid >> 6) + it * 4;
            int n = tid & 63;
            Bs[k][n] = Bm[(size_t)(k0 + k) * ldb + n0 + n];
        }
        __syncthreads();
        #pragma unroll
        for (int kk = 0; kk < 16; ++kk) {
            float a[4], b[4];
            #pragma unroll
            for (int i = 0; i < 4; ++i) a[i] = As[kk][ty * 4 + i];
            #pragma unroll
            for (int j = 0; j < 4; ++j) b[j] = Bs[kk][tx * 4 + j];
            #pragma unroll
            for (int i = 0; i < 4; ++i)
                #pragma unroll
                for (int j = 0; j < 4; ++j)
                    acc[i][j] = fmaf(a[i], b[j], acc[i][j]);
        }
        __syncthreads();
    }

    #pragma unroll
    for (int i = 0; i < 4; ++i) {
        int gm = m0 + ty * 4 + i;
        float bv = to_f(bias[gm]);
        #pragma unroll
        for (int j = 0; j < 4; ++j) {
            int gn = n0 + tx * 4 + j;
            C[(size_t)gm * ldc + gn] = softplus_f(acc[i][j] + bv);
        }
    }
}

// ---------------- conv v2: 8 outputs per thread along L ----------------
// u^T[d][r0..r0+7] = silu(conv(x^T)+b); batch-causal padding at l%1024 < 3.
__global__ __launch_bounds__(256) void conv_silu_T8(
    const bf16* __restrict__ xzT,
    const bf16* __restrict__ w,
    const bf16* __restrict__ bias,
    bf16* __restrict__ utT)
{
    int t = blockIdx.x * 256 + threadIdx.x;       // (DINNER*ROWS/8) threads
    int r0 = (t * 8) & (ROWS - 1);
    int d = t >> 8;                               // (t*8) >> 11

    const ushort* xp = (const ushort*)xzT + (size_t)d * ROWS + r0;
    float x[11];                                  // rows r0-3 .. r0+7
    us8 cur = *(const us8*)xp;
    #pragma unroll
    for (int j = 0; j < 8; ++j) x[3 + j] = bfu(cur[j]);
    if ((r0 & (SEQLEN - 1)) != 0) {
        ushort4 pv = *(const ushort4*)(xp - 4);   // rows r0-4..r0-1
        x[0] = bfu(pv.y); x[1] = bfu(pv.z); x[2] = bfu(pv.w);
    } else {
        x[0] = x[1] = x[2] = 0.f;                 // causal pad at batch start
    }

    ushort4 wv = *(const ushort4*)((const ushort*)w + d * 4);
    float w0 = bfu(wv.x), w1 = bfu(wv.y), w2 = bfu(wv.z), w3 = bfu(wv.w);
    float bv = to_f(bias[d]);

    us8 o;
    #pragma unroll
    for (int j = 0; j < 8; ++j) {
        float acc = bv;
        acc = fmaf(x[j],     w0, acc);
        acc = fmaf(x[j + 1], w1, acc);
        acc = fmaf(x[j + 2], w2, acc);
        acc = fmaf(x[j + 3], w3, acc);
        o[j] = bf_bits(silu_f(acc));
    }
    *(us8*)((ushort*)utT + (size_t)d * ROWS + r0) = o;
}

// ---------------- scan v7: 16 chunks x 64 steps, batched epilogue, exp2 path ----
// Block = 1024 thr = 16 L-chunks(waves) x 4 d x 16 n; grid = BATCH * DINNER/4 = 1024.
#define SCHUNK 16
#define SSTEPS (SEQLEN / SCHUNK)   // 64
__global__ __launch_bounds__(1024) void scan_kernel7(
    const float* __restrict__ deltaT,  // (DINNER, ROWS) f32
    const bf16*  __restrict__ utT,     // (DINNER, ROWS)
    const float* __restrict__ xdT,     // (96, ROWS): row 64+n = B_n, 80+n = C_n
    const bf16*  __restrict__ xzT,     // (4096, ROWS): z at row DINNER+d
    const bf16*  __restrict__ A_log,   // (DINNER,16)
    const bf16*  __restrict__ Dp,      // (DINNER,)
    bf16* __restrict__ outz)           // (ROWS, DINNER)
{
    __shared__ float sH[SCHUNK][64], sP[SCHUNK][64];
    const int tid = threadIdx.x;
    const int c = tid >> 6;            // chunk (== wave id), 0..15
    const int w = tid & 63;
    const int dg = (tid >> 4) & 3;
    const int n = tid & 15;
    const int b = blockIdx.x >> 9;
    const int d = ((blockIdx.x & 511) << 2) + dg;
    const int row0 = b * SEQLEN + c * SSTEPS;

    const float Aa2 = -expf(to_f(A_log[d * DSTATE + n])) * LOG2E;
    const float Dv16 = to_f(Dp[d]) * (1.f / 16.f);

    const float*  dp = deltaT + (size_t)d * ROWS + row0;
    const ushort* up = (const ushort*)utT + (size_t)d * ROWS + row0;
    const ushort* zp = (const ushort*)xzT + (size_t)(DINNER + d) * ROWS + row0;
    const float*  Bp = xdT + (size_t)(64 + n) * ROWS + row0;
    const float*  Cp = xdT + (size_t)(80 + n) * ROWS + row0;

    // phase 1: local scan; decay product via sum-of-delta + one exp2
    float h = 0.f, sd = 0.f;
    for (int i0 = 0; i0 < SSTEPS; i0 += 4) {
        float4  dv4 = *(const float4*)(dp + i0);
        ushort4 uv4 = *(const ushort4*)(up + i0);
        float4  Bv4 = *(const float4*)(Bp + i0);
        float dv[4] = {dv4.x, dv4.y, dv4.z, dv4.w};
        float uv[4] = {bfu(uv4.x), bfu(uv4.y), bfu(uv4.z), bfu(uv4.w)};
        float Bv[4] = {Bv4.x, Bv4.y, Bv4.z, Bv4.w};
        #pragma unroll
        for (int j = 0; j < 4; ++j) {
            float a = fexp2(dv[j] * Aa2);
            h = fmaf(a, h, dv[j] * Bv[j] * uv[j]);
            sd += dv[j];
        }
    }
    sH[c][w] = h;
    sP[c][w] = fexp2(sd * Aa2);
    __syncthreads();

    // phase 2: fold preceding chunk summaries (<=15 fma, wave-uniform)
    float hin = 0.f;
    for (int cc = 0; cc < c; ++cc)
        hin = fmaf(sP[cc][w], hin, sH[cc][w]);

    // phase 3: rescan with correct incoming state; batched epilogue per 4 steps
    h = hin;
    for (int i0 = 0; i0 < SSTEPS; i0 += 4) {
        float4  dv4 = *(const float4*)(dp + i0);
        ushort4 uv4 = *(const ushort4*)(up + i0);
        float4  Bv4 = *(const float4*)(Bp + i0);
        float4  Cv4 = *(const float4*)(Cp + i0);
        ushort4 zv4 = *(const ushort4*)(zp + i0);
        float dv[4] = {dv4.x, dv4.y, dv4.z, dv4.w};
        float uv[4] = {bfu(uv4.x), bfu(uv4.y), bfu(uv4.z), bfu(uv4.w)};
        float Bv[4] = {Bv4.x, Bv4.y, Bv4.z, Bv4.w};
        float Cv[4] = {Cv4.x, Cv4.y, Cv4.z, Cv4.w};
        float zv[4] = {bfu(zv4.x), bfu(zv4.y), bfu(zv4.z), bfu(zv4.w)};
        float y[4];
        #pragma unroll
        for (int j = 0; j < 4; ++j) {
            float a = fexp2(dv[j] * Aa2);
            h = fmaf(a, h, dv[j] * Bv[j] * uv[j]);
            // fold +u*D into the reduction: 16 lanes each add u*D/16
            float p = fmaf(uv[j], Dv16, h * Cv[j]);
            p += __shfl_xor(p, 1, 16);
            p += __shfl_xor(p, 2, 16);
            p += __shfl_xor(p, 4, 16);
            p += __shfl_xor(p, 8, 16);
            y[j] = p;                  // valid in all 16 n-lanes
        }
        // batched store: lane (n) with n&3==0 stores step q2 = n>>2
        float t0 = (n & 4) ? y[1] : y[0];
        float t1 = (n & 4) ? y[3] : y[2];
        float yv = (n & 8) ? t1 : t0;
        float z0 = (n & 4) ? zv[1] : zv[0];
        float z1 = (n & 4) ? zv[3] : zv[2];
        float zz = (n & 8) ? z1 : z0;
        if ((n & 3) == 0) {
            int q2 = n >> 2;
            outz[(size_t)(row0 + i0 + q2) * DINNER + d] =
                __float2bfloat16(yv * silu_f(zz));
        }
    }
}

extern "C" void kernel_launch(void* const* d_in, const int* in_sizes, int n_in,
                              void* d_out, int out_size, void* d_ws, size_t ws_size,
                              hipStream_t stream) {
    static const size_t SZ[10] = {
        (size_t)BATCH * SEQLEN * DMODEL,        // hidden_states
        (size_t)2 * DINNER * DMODEL,            // in_proj_w
        (size_t)DINNER * 4,                     // conv1d_w
        (size_t)DINNER,                         // conv1d_b
        (size_t)(DTRANK + 2 * DSTATE) * DINNER, // x_proj_w
        (size_t)DINNER * DTRANK,                // dt_proj_w
        (size_t)DINNER,                         // dt_proj_b
        (size_t)DINNER * DSTATE,                // A_log
        (size_t)DINNER,                         // D_param
        (size_t)DMODEL * DINNER                 // out_proj_w
    };
    size_t tot_in = 0;
    for (int i = 0; i < 10; ++i) tot_in += SZ[i];

    char* p = (char*)d_ws;
    int* flag = (int*)p;                     p += 64;
    bf16* inb = (bf16*)p;                    p += tot_in * 2;
    bf16* xzT = (bf16*)p;                    p += (size_t)4096 * ROWS * 2;
    bf16* utT = (bf16*)p;                    p += (size_t)DINNER * ROWS * 2;
    float* xdT = (float*)p;                  p += (size_t)96 * ROWS * 4;
    float* deltaT = (float*)p;               p += (size_t)DINNER * ROWS * 4;
    bf16* outz = (bf16*)p;                   p += (size_t)ROWS * DINNER * 2;
    float* part = (float*)p;                 p += (size_t)2 * ROWS * DMODEL * 4;
    size_t needed = (size_t)(p - (char*)d_ws);
    if (ws_size < needed) return;

    dim3 blk(256);

    // 0) detect dtype (block 0) + zero xdT (blocks 1..)
    prep_kernel<<<1 + (96 * ROWS + 255) / 256, blk, 0, stream>>>(
        (const unsigned short*)d_in[0], flag, xdT, 96 * ROWS);

    bf16* inp[10];
    {
        size_t off = 0;
        for (int i = 0; i < 10; ++i) { inp[i] = inb + off; off += SZ[i]; }
    }
    SrcPtrs sp;
    for (int i = 0; i < 10; ++i) sp.p[i] = d_in[i];
    convert_all<<<(int)((tot_in / 4 + 255) / 256), blk, 0, stream>>>(sp, inb, flag);

    const bf16* hs        = inp[0];
    const bf16* in_proj_w = inp[1];
    const bf16* conv_w    = inp[2];
    const bf16* conv_b    = inp[3];
    const bf16* x_proj_w  = inp[4];
    const bf16* dt_proj_w = inp[5];
    const bf16* dt_proj_b = inp[6];
    const bf16* A_log     = inp[7];
    const bf16* Dp        = inp[8];
    const bf16* out_proj_w= inp[9];

    // 1) xzT = (hs @ in_proj_w^T)^T : M=4096(e) N=2048(row) K=1024  (MFMA, roles swapped)
    gemm_mfma<0><<<dim3(ROWS / 128, 4096 / 128, 1), blk, 0, stream>>>(
        in_proj_w, DMODEL, hs, DMODEL, xzT, ROWS, DMODEL, 0);

    // 2) utT = silu(causal depthwise conv along L), d-major, 8 outputs/thread
    conv_silu_T8<<<(DINNER * ROWS / 8) / 256, blk, 0, stream>>>(xzT, conv_w, conv_b, utT);

    // 3) xdT[r][row] = sum_d utT[d][row] * x_proj_w[r][d]  (gemm_tn, transposed out, split-K=4)
    gemm_tn_atomic<<<dim3(2, ROWS / 64, 4), blk, 0, stream>>>(
        utT, ROWS, x_proj_w, DINNER, xdT, ROWS, ROWS, 96, DINNER / 4);

    // 4) deltaT[d][row] = softplus(sum_r dtw[d][r]*xdT[r][row] + dtb[d])
    gemm_nt_dt<<<dim3(ROWS / 64, DINNER / 64), blk, 0, stream>>>(
        dt_proj_w, DTRANK, xdT, ROWS, deltaT, ROWS, DTRANK, dt_proj_b);

    // 5) chunk-parallel selective scan (16 chunks, 1024-thr blocks) -> outz (row-major)
    scan_kernel7<<<BATCH * (DINNER / 4), dim3(1024), 0, stream>>>(
        deltaT, utT, xdT, xzT, A_log, Dp, outz);

    // 6) out = outz @ out_proj_w^T  M=2048 N=1024 K=2048  (MFMA split-K=2 -> f32 partials)
    gemm_mfma<2><<<dim3(DMODEL / 128, ROWS / 128, 2), blk, 0, stream>>>(
        outz, DINNER, out_proj_w, DINNER, part, DMODEL, DINNER / 2, (size_t)ROWS * DMODEL);

    // 6b) out = cvt(part0 + part1)
    sum_store<<<(ROWS * DMODEL / 4 + 255) / 256, blk, 0, stream>>>(
        part, part + (size_t)ROWS * DMODEL, d_out, flag, ROWS * DMODEL / 4);
}

// Round 11
// 349.386 us; speedup vs baseline: 5.1376x; 1.0824x over previous
//
#include <hip/hip_runtime.h>
#include <hip/hip_bf16.h>

// Shapes: B=2, L=1024, D_MODEL=1024, D_INNER=2048, D_STATE=16, D_CONV=4, DT_RANK=64
#define BATCH 2
#define SEQLEN 1024
#define DMODEL 1024
#define DINNER 2048
#define DSTATE 16
#define DTRANK 64
#define ROWS (BATCH * SEQLEN) // 2048
#define LOG2E 1.44269504088896340736f

using bf16 = __hip_bfloat16;
typedef __bf16 bf16x8 __attribute__((ext_vector_type(8)));
typedef float f32x4 __attribute__((ext_vector_type(4)));
typedef unsigned short us8 __attribute__((ext_vector_type(8)));

__device__ __forceinline__ float to_f(float x) { return x; }
__device__ __forceinline__ float to_f(bf16 x) { return __bfloat162float(x); }

__device__ __forceinline__ float fexp2(float x) { return __builtin_amdgcn_exp2f(x); }

__device__ __forceinline__ float bfu(unsigned short u) {
    union { unsigned int i; float f; } v;
    v.i = ((unsigned int)u) << 16;
    return v.f;
}

__device__ __forceinline__ unsigned short bf_bits(float x) {
    bf16 h = __float2bfloat16(x);
    union { bf16 b; unsigned short u; } cv;
    cv.b = h;
    return cv.u;
}

__device__ __forceinline__ float softplus_f(float x) {
    return fmaxf(x, 0.f) + log1pf(expf(-fabsf(x)));
}
// fast silu
__device__ __forceinline__ float silu_f(float x) {
    return x * __builtin_amdgcn_rcpf(1.f + fexp2(-x * LOG2E));
}

// async 16B global -> LDS
__device__ __forceinline__ void gload16(const void* g, void* l) {
    __builtin_amdgcn_global_load_lds(
        (const __attribute__((address_space(1))) void*)g,
        (__attribute__((address_space(3))) void*)l, 16, 0, 0);
}

// ---------- prep: block 0 = dtype detect; blocks 1.. zero xd ----------
__global__ __launch_bounds__(256) void prep_kernel(const unsigned short* hs, int* flag,
                                                   float* zbuf, int nzero) {
    if (blockIdx.x == 0) {
        __shared__ int cnt[256];
        int c = 0;
        for (int i = threadIdx.x; i < 8192; i += 256) {
            int e = (hs[i] >> 7) & 0xFF;
            if (e == 0 || e == 0xFF || e < 96 || e > 159) c++;
        }
        cnt[threadIdx.x] = c;
        __syncthreads();
        for (int s = 128; s > 0; s >>= 1) {
            if (threadIdx.x < s) cnt[threadIdx.x] += cnt[threadIdx.x + s];
            __syncthreads();
        }
        if (threadIdx.x == 0) *flag = (cnt[0] < 512) ? 1 : 0;
    } else {
        int i = (blockIdx.x - 1) * 256 + threadIdx.x;
        if (i < nzero) zbuf[i] = 0.f;
    }
}

// ---------- fused convert of all 10 inputs to one contiguous bf16 arena ----------
struct SrcPtrs { const void* p[10]; };

__device__ __constant__ const size_t SEG_OFF[11] = {
    0, 2097152, 6291456, 6299648, 6301696, 6498304,
    6629376, 6631424, 6664192, 6666240, 8763392
};

__global__ __launch_bounds__(256) void convert_all(SrcPtrs s, bf16* __restrict__ dst,
                                                   const int* __restrict__ flag) {
    size_t e = ((size_t)blockIdx.x * 256 + threadIdx.x) * 4;
    if (e >= SEG_OFF[10]) return;
    int seg = 0;
    #pragma unroll
    for (int i = 1; i < 10; ++i) if (e >= SEG_OFF[i]) seg = i;
    size_t loc = e - SEG_OFF[seg];
    if (*flag) {
        ushort4 v = ((const ushort4*)s.p[seg])[loc / 4];
        ((ushort4*)(dst + e))[0] = v;
    } else {
        float4 v = ((const float4*)s.p[seg])[loc / 4];
        ushort4 o;
        o.x = bf_bits(v.x); o.y = bf_bits(v.y);
        o.z = bf_bits(v.z); o.w = bf_bits(v.w);
        ((ushort4*)(dst + e))[0] = o;
    }
}

// ---------------- MFMA GEMM: C[m][n] = sum_k A[m][k]*B[n][k], bf16 in, 128x128 tile ----
// OUTMODE: 0 = bf16 store
//          2 = f32 store at C + blockIdx.z*pstride (split-K partials)
//          3 = f32 atomicAdd, store only col < 96 (x_proj)
//          4 = f32 store of softplus(v + bias[row]) (dt_proj -> deltaT)
template <int OUTMODE>
__global__ __launch_bounds__(256) void gemm_mfma(
    const bf16* __restrict__ A, int lda,
    const bf16* __restrict__ Bm, int ldb,
    void* __restrict__ C, int ldc,
    int Kspl, size_t pstride,
    const bf16* __restrict__ bias)
{
    __shared__ __align__(16) __bf16 sA[128 * 32];
    __shared__ __align__(16) __bf16 sB[128 * 32];
    const int tid = threadIdx.x;
    const int m0 = blockIdx.y * 128;
    const int n0 = blockIdx.x * 128;
    const int wid = tid >> 6, ln = tid & 63;
    const int wy = (wid >> 1) * 64, wx = (wid & 1) * 64;
    const int q = ln >> 4, m16 = ln & 15;
    const int kbeg = blockIdx.z * Kspl;

    f32x4 acc[4][4] = {};

    for (int k0 = kbeg; k0 < kbeg + Kspl; k0 += 32) {
        #pragma unroll
        for (int i = 0; i < 2; ++i) {
            int idx = tid + i * 256;
            int r = idx >> 2, c = (idx & 3) * 8;
            gload16(&A[(size_t)(m0 + r) * lda + k0 + c], &sA[idx * 8]);
        }
        #pragma unroll
        for (int i = 0; i < 2; ++i) {
            int idx = tid + i * 256;
            int r = idx >> 2, c = (idx & 3) * 8;
            gload16(&Bm[(size_t)(n0 + r) * ldb + k0 + c], &sB[idx * 8]);
        }
        __syncthreads();
        bf16x8 a[4], b[4];
        #pragma unroll
        for (int i = 0; i < 4; ++i)
            a[i] = *(const bf16x8*)&sA[(wy + i * 16 + m16) * 32 + q * 8];
        #pragma unroll
        for (int j = 0; j < 4; ++j)
            b[j] = *(const bf16x8*)&sB[(wx + j * 16 + m16) * 32 + q * 8];
        #pragma unroll
        for (int i = 0; i < 4; ++i)
            #pragma unroll
            for (int j = 0; j < 4; ++j)
                acc[i][j] = __builtin_amdgcn_mfma_f32_16x16x32_bf16(a[i], b[j], acc[i][j], 0, 0, 0);
        __syncthreads();
    }

    #pragma unroll
    for (int i = 0; i < 4; ++i) {
        #pragma unroll
        for (int j = 0; j < 4; ++j) {
            #pragma unroll
            for (int r = 0; r < 4; ++r) {
                int row = m0 + wy + i * 16 + q * 4 + r;
                int col = n0 + wx + j * 16 + m16;
                size_t idx = (size_t)row * ldc + col;
                float v = acc[i][j][r];
                if constexpr (OUTMODE == 0) {
                    ((bf16*)C)[idx] = __float2bfloat16(v);
                } else if constexpr (OUTMODE == 2) {
                    ((float*)C + blockIdx.z * pstride)[idx] = v;
                } else if constexpr (OUTMODE == 3) {
                    if (col < 96) atomicAdd((float*)C + idx, v);
                } else if constexpr (OUTMODE == 4) {
                    ((float*)C)[idx] = softplus_f(v + to_f(bias[row]));
                }
            }
        }
    }
}

// sum the two split-K partials, store to d_out as bf16 or f32 per flag
__global__ __launch_bounds__(256) void sum_store(
    const float* __restrict__ p0, const float* __restrict__ p1,
    void* __restrict__ out, const int* __restrict__ flag, int n4)
{
    int i = blockIdx.x * 256 + threadIdx.x;
    if (i >= n4) return;
    float4 a = ((const float4*)p0)[i];
    float4 b = ((const float4*)p1)[i];
    float4 sv; sv.x = a.x + b.x; sv.y = a.y + b.y; sv.z = a.z + b.z; sv.w = a.w + b.w;
    if (*flag) {
        ushort4 o;
        o.x = bf_bits(sv.x); o.y = bf_bits(sv.y);
        o.z = bf_bits(sv.z); o.w = bf_bits(sv.w);
        ((ushort4*)out)[i] = o;
    } else {
        ((float4*)out)[i] = sv;
    }
}

// ---------------- transpose utT (d,row) -> ut (row,d), 64x64 LDS tiles ----------------
__global__ __launch_bounds__(256) void transpose_bf16(
    const ushort* __restrict__ src,   // (DINNER, ROWS)
    ushort* __restrict__ dst)         // (ROWS, DINNER)
{
    __shared__ ushort t[64][65];
    const int bx = blockIdx.x;        // row-tile
    const int by = blockIdx.y;        // d-tile
    const int tid = threadIdx.x;
    const int lr = tid & 63;
    const int ld = tid >> 6;          // 0..3
    #pragma unroll
    for (int i = 0; i < 16; ++i) {
        int d = ld + i * 4;
        t[d][lr] = src[(size_t)(by * 64 + d) * ROWS + bx * 64 + lr];
    }
    __syncthreads();
    #pragma unroll
    for (int i = 0; i < 16; ++i) {
        int r = ld + i * 4;
        dst[(size_t)(bx * 64 + r) * DINNER + by * 64 + lr] = t[lr][r];
    }
}

// ---------------- xd post: xd (2048,96) f32 -> xdT (96,2048) f32 + xd_bf bf16 ----------
__global__ __launch_bounds__(256) void xd_post(
    const float* __restrict__ xd,
    float* __restrict__ xdT,
    bf16* __restrict__ xd_bf)
{
    __shared__ float t[96][65];
    const int row0 = blockIdx.x * 64;
    const int tid = threadIdx.x;
    for (int i = tid; i < 64 * 96; i += 256) {
        int row = i / 96, r = i - row * 96;
        float v = xd[(size_t)(row0 + row) * 96 + r];
        t[r][row] = v;
        xd_bf[(size_t)(row0 + row) * 96 + r] = __float2bfloat16(v);
    }
    __syncthreads();
    for (int i = tid; i < 96 * 64; i += 256) {
        int r = i >> 6, row = i & 63;
        xdT[(size_t)r * ROWS + row0 + row] = t[r][row];
    }
}

// ---------------- conv: 8 outputs per thread along L ----------------
__global__ __launch_bounds__(256) void conv_silu_T8(
    const bf16* __restrict__ xzT,
    const bf16* __restrict__ w,
    const bf16* __restrict__ bias,
    bf16* __restrict__ utT)
{
    int t = blockIdx.x * 256 + threadIdx.x;
    int r0 = (t * 8) & (ROWS - 1);
    int d = t >> 8;

    const ushort* xp = (const ushort*)xzT + (size_t)d * ROWS + r0;
    float x[11];
    us8 cur = *(const us8*)xp;
    #pragma unroll
    for (int j = 0; j < 8; ++j) x[3 + j] = bfu(cur[j]);
    if ((r0 & (SEQLEN - 1)) != 0) {
        ushort4 pv = *(const ushort4*)(xp - 4);
        x[0] = bfu(pv.y); x[1] = bfu(pv.z); x[2] = bfu(pv.w);
    } else {
        x[0] = x[1] = x[2] = 0.f;
    }

    ushort4 wv = *(const ushort4*)((const ushort*)w + d * 4);
    float w0 = bfu(wv.x), w1 = bfu(wv.y), w2 = bfu(wv.z), w3 = bfu(wv.w);
    float bv = to_f(bias[d]);

    us8 o;
    #pragma unroll
    for (int j = 0; j < 8; ++j) {
        float acc = bv;
        acc = fmaf(x[j],     w0, acc);
        acc = fmaf(x[j + 1], w1, acc);
        acc = fmaf(x[j + 2], w2, acc);
        acc = fmaf(x[j + 3], w3, acc);
        o[j] = bf_bits(silu_f(acc));
    }
    *(us8*)((ushort*)utT + (size_t)d * ROWS + r0) = o;
}

// ---------------- scan v8: prefetched streams, batched epilogue ----------------
#define SCHUNK 16
#define SSTEPS (SEQLEN / SCHUNK)   // 64
__global__ __launch_bounds__(1024) void scan_kernel8(
    const float* __restrict__ deltaT,  // (DINNER, ROWS) f32
    const bf16*  __restrict__ utT,     // (DINNER, ROWS)
    const float* __restrict__ xdT,     // (96, ROWS): row 64+n = B_n, 80+n = C_n
    const bf16*  __restrict__ xzT,     // (4096, ROWS): z at row DINNER+d
    const bf16*  __restrict__ A_log,   // (DINNER,16)
    const bf16*  __restrict__ Dp,      // (DINNER,)
    bf16* __restrict__ outz)           // (ROWS, DINNER)
{
    __shared__ float sH[SCHUNK][64], sP[SCHUNK][64];
    const int tid = threadIdx.x;
    const int c = tid >> 6;
    const int w = tid & 63;
    const int n = tid & 15;
    const int b = blockIdx.x >> 9;
    const int d = ((blockIdx.x & 511) << 2) + ((tid >> 4) & 3);
    const int row0 = b * SEQLEN + c * SSTEPS;

    const float Aa2 = -expf(to_f(A_log[d * DSTATE + n])) * LOG2E;
    const float Dv16 = to_f(Dp[d]) * (1.f / 16.f);

    const float*  dp = deltaT + (size_t)d * ROWS + row0;
    const ushort* up = (const ushort*)utT + (size_t)d * ROWS + row0;
    const ushort* zp = (const ushort*)xzT + (size_t)(DINNER + d) * ROWS + row0;
    const float*  Bp = xdT + (size_t)(64 + n) * ROWS + row0;
    const float*  Cp = xdT + (size_t)(80 + n) * ROWS + row0;

    // ---- phase 1: local scan with one-iteration-ahead prefetch ----
    float h = 0.f, sd = 0.f;
    {
        float4  dv4 = *(const float4*)(dp);
        ushort4 uv4 = *(const ushort4*)(up);
        float4  Bv4 = *(const float4*)(Bp);
        for (int i0 = 0; i0 < SSTEPS; i0 += 4) {
            float4 dvc = dv4; ushort4 uvc = uv4; float4 Bvc = Bv4;
            if (i0 + 4 < SSTEPS) {
                dv4 = *(const float4*)(dp + i0 + 4);
                uv4 = *(const ushort4*)(up + i0 + 4);
                Bv4 = *(const float4*)(Bp + i0 + 4);
            }
            float dv[4] = {dvc.x, dvc.y, dvc.z, dvc.w};
            float uv[4] = {bfu(uvc.x), bfu(uvc.y), bfu(uvc.z), bfu(uvc.w)};
            float Bv[4] = {Bvc.x, Bvc.y, Bvc.z, Bvc.w};
            #pragma unroll
            for (int j = 0; j < 4; ++j) {
                float a = fexp2(dv[j] * Aa2);
                h = fmaf(a, h, dv[j] * Bv[j] * uv[j]);
                sd += dv[j];
            }
        }
    }
    sH[c][w] = h;
    sP[c][w] = fexp2(sd * Aa2);
    __syncthreads();

    // ---- phase 2: fold preceding chunk summaries ----
    float hin = 0.f;
    for (int cc = 0; cc < c; ++cc)
        hin = fmaf(sP[cc][w], hin, sH[cc][w]);

    // ---- phase 3: rescan with prefetch, batched epilogue ----
    h = hin;
    {
        float4  dv4 = *(const float4*)(dp);
        ushort4 uv4 = *(const ushort4*)(up);
        float4  Bv4 = *(const float4*)(Bp);
        float4  Cv4 = *(const float4*)(Cp);
        ushort4 zv4 = *(const ushort4*)(zp);
        for (int i0 = 0; i0 < SSTEPS; i0 += 4) {
            float4 dvc = dv4; ushort4 uvc = uv4; float4 Bvc = Bv4;
            float4 Cvc = Cv4; ushort4 zvc = zv4;
            if (i0 + 4 < SSTEPS) {
                dv4 = *(const float4*)(dp + i0 + 4);
                uv4 = *(const ushort4*)(up + i0 + 4);
                Bv4 = *(const float4*)(Bp + i0 + 4);
                Cv4 = *(const float4*)(Cp + i0 + 4);
                zv4 = *(const ushort4*)(zp + i0 + 4);
            }
            float dv[4] = {dvc.x, dvc.y, dvc.z, dvc.w};
            float uv[4] = {bfu(uvc.x), bfu(uvc.y), bfu(uvc.z), bfu(uvc.w)};
            float Bv[4] = {Bvc.x, Bvc.y, Bvc.z, Bvc.w};
            float Cv[4] = {Cvc.x, Cvc.y, Cvc.z, Cvc.w};
            float zv[4] = {bfu(zvc.x), bfu(zvc.y), bfu(zvc.z), bfu(zvc.w)};
            float y[4];
            #pragma unroll
            for (int j = 0; j < 4; ++j) {
                float a = fexp2(dv[j] * Aa2);
                h = fmaf(a, h, dv[j] * Bv[j] * uv[j]);
                float p = fmaf(uv[j], Dv16, h * Cv[j]);
                p += __shfl_xor(p, 1, 16);
                p += __shfl_xor(p, 2, 16);
                p += __shfl_xor(p, 4, 16);
                p += __shfl_xor(p, 8, 16);
                y[j] = p;
            }
            float t0 = (n & 4) ? y[1] : y[0];
            float t1 = (n & 4) ? y[3] : y[2];
            float yv = (n & 8) ? t1 : t0;
            float z0 = (n & 4) ? zv[1] : zv[0];
            float z1 = (n & 4) ? zv[3] : zv[2];
            float zz = (n & 8) ? z1 : z0;
            if ((n & 3) == 0) {
                int q2 = n >> 2;
                outz[(size_t)(row0 + i0 + q2) * DINNER + d] =
                    __float2bfloat16(yv * silu_f(zz));
            }
        }
    }
}

extern "C" void kernel_launch(void* const* d_in, const int* in_sizes, int n_in,
                              void* d_out, int out_size, void* d_ws, size_t ws_size,
                              hipStream_t stream) {
    static const size_t SZ[10] = {
        (size_t)BATCH * SEQLEN * DMODEL,        // hidden_states
        (size_t)2 * DINNER * DMODEL,            // in_proj_w
        (size_t)DINNER * 4,                     // conv1d_w
        (size_t)DINNER,                         // conv1d_b
        (size_t)(DTRANK + 2 * DSTATE) * DINNER, // x_proj_w
        (size_t)DINNER * DTRANK,                // dt_proj_w
        (size_t)DINNER,                         // dt_proj_b
        (size_t)DINNER * DSTATE,                // A_log
        (size_t)DINNER,                         // D_param
        (size_t)DMODEL * DINNER                 // out_proj_w
    };
    size_t tot_in = 0;
    for (int i = 0; i < 10; ++i) tot_in += SZ[i];

    char* p = (char*)d_ws;
    int* flag = (int*)p;                     p += 64;
    bf16* inb = (bf16*)p;                    p += tot_in * 2;
    bf16* xzT = (bf16*)p;                    p += (size_t)4096 * ROWS * 2;
    bf16* utT = (bf16*)p;                    p += (size_t)DINNER * ROWS * 2;
    bf16* ut  = (bf16*)p;                    p += (size_t)ROWS * DINNER * 2;
    float* xd = (float*)p;                   p += (size_t)ROWS * 96 * 4;
    bf16* xd_bf = (bf16*)p;                  p += (size_t)ROWS * 96 * 2;
    float* xdT = (float*)p;                  p += (size_t)96 * ROWS * 4;
    float* deltaT = (float*)p;               p += (size_t)DINNER * ROWS * 4;
    bf16* outz = (bf16*)p;                   p += (size_t)ROWS * DINNER * 2;
    float* part = (float*)p;                 p += (size_t)2 * ROWS * DMODEL * 4;
    size_t needed = (size_t)(p - (char*)d_ws);
    if (ws_size < needed) return;

    dim3 blk(256);

    // 0) detect dtype + zero xd (for atomic accumulation)
    prep_kernel<<<1 + (ROWS * 96 + 255) / 256, blk, 0, stream>>>(
        (const unsigned short*)d_in[0], flag, xd, ROWS * 96);

    bf16* inp[10];
    {
        size_t off = 0;
        for (int i = 0; i < 10; ++i) { inp[i] = inb + off; off += SZ[i]; }
    }
    SrcPtrs sp;
    for (int i = 0; i < 10; ++i) sp.p[i] = d_in[i];
    convert_all<<<(int)((tot_in / 4 + 255) / 256), blk, 0, stream>>>(sp, inb, flag);

    const bf16* hs        = inp[0];
    const bf16* in_proj_w = inp[1];
    const bf16* conv_w    = inp[2];
    const bf16* conv_b    = inp[3];
    const bf16* x_proj_w  = inp[4];
    const bf16* dt_proj_w = inp[5];
    const bf16* dt_proj_b = inp[6];
    const bf16* A_log     = inp[7];
    const bf16* Dp        = inp[8];
    const bf16* out_proj_w= inp[9];

    // 1) xzT = (hs @ in_proj_w^T)^T : M=4096(e) N=2048(row) K=1024
    gemm_mfma<0><<<dim3(ROWS / 128, 4096 / 128, 1), blk, 0, stream>>>(
        in_proj_w, DMODEL, hs, DMODEL, xzT, ROWS, DMODEL, 0, nullptr);

    // 2) utT = silu(causal depthwise conv along L), d-major
    conv_silu_T8<<<(DINNER * ROWS / 8) / 256, blk, 0, stream>>>(xzT, conv_w, conv_b, utT);

    // 2b) ut = utT^T (row-major, for MFMA x_proj)
    transpose_bf16<<<dim3(ROWS / 64, DINNER / 64), blk, 0, stream>>>(
        (const ushort*)utT, (ushort*)ut);

    // 3) xd[row][r] = sum_d ut[row][d] * x_proj_w[r][d]  (MFMA, split-K=4, atomic f32)
    gemm_mfma<3><<<dim3(1, ROWS / 128, 4), blk, 0, stream>>>(
        ut, DINNER, x_proj_w, DINNER, xd, 96, DINNER / 4, 0, nullptr);

    // 3b) xdT = xd^T (f32, scan layout) + xd_bf (bf16 row-major, dt GEMM operand)
    xd_post<<<ROWS / 64, blk, 0, stream>>>(xd, xdT, xd_bf);

    // 4) deltaT[d][row] = softplus(sum_r dtw[d][r]*xd[row][r] + dtb[d])  (MFMA K=64)
    gemm_mfma<4><<<dim3(ROWS / 128, DINNER / 128, 1), blk, 0, stream>>>(
        dt_proj_w, DTRANK, xd_bf, 96, deltaT, ROWS, DTRANK, 0, dt_proj_b);

    // 5) chunk-parallel selective scan (prefetched) -> outz (row-major)
    scan_kernel8<<<BATCH * (DINNER / 4), dim3(1024), 0, stream>>>(
        deltaT, utT, xdT, xzT, A_log, Dp, outz);

    // 6) out = outz @ out_proj_w^T  (MFMA split-K=2 -> f32 partials)
    gemm_mfma<2><<<dim3(DMODEL / 128, ROWS / 128, 2), blk, 0, stream>>>(
        outz, DINNER, out_proj_w, DINNER, part, DMODEL, DINNER / 2, (size_t)ROWS * DMODEL, nullptr);

    // 6b) out = cvt(part0 + part1)
    sum_store<<<(ROWS * DMODEL / 4 + 255) / 256, blk, 0, stream>>>(
        part, part + (size_t)ROWS * DMODEL, d_out, flag, ROWS * DMODEL / 4);
}